// Round 1
// baseline (1421.157 us; speedup 1.0000x reference)
//
#include <hip/hip_runtime.h>
#include <stdint.h>

#define L_ 8
#define D_ 256
#define H_ 8
#define DK_ 32
#define FF_ 1024
#define R_ 37
#define N_ 1024
#define JS_ 4
#define IB_ 32

typedef float f4v __attribute__((ext_vector_type(4)));
typedef short b8v __attribute__((ext_vector_type(8)));

__device__ __forceinline__ ushort f2b(float f){
  union { float f; uint32_t u; } x; x.f = f;
  return (ushort)((x.u + 0x7FFFu + ((x.u >> 16) & 1u)) >> 16);
}
__device__ __forceinline__ float wred_max(float v){
  #pragma unroll
  for (int o = 32; o; o >>= 1) v = fmaxf(v, __shfl_xor(v, o));
  return v;
}
__device__ __forceinline__ float wred_sum(float v){
  #pragma unroll
  for (int o = 32; o; o >>= 1) v += __shfl_xor(v, o);
  return v;
}

// ---------------- weight transpose + cast: src [L][K][Nc] f32 -> dst [L][Nc][K] bf16
__global__ __launch_bounds__(256)
void wcast_kernel(const float* __restrict__ src, ushort* __restrict__ dst, int K, int Nc){
  __shared__ float t[32][33];
  int l = blockIdx.z;
  long base = (long)l * K * Nc;
  int n0 = blockIdx.x * 32, k0 = blockIdx.y * 32;
  int tx = threadIdx.x, ty = threadIdx.y; // (32,8)
  #pragma unroll
  for (int r = 0; r < 32; r += 8)
    t[ty + r][tx] = src[base + (long)(k0 + ty + r) * Nc + n0 + tx];
  __syncthreads();
  #pragma unroll
  for (int r = 0; r < 32; r += 8)
    dst[base + (long)(n0 + ty + r) * K + k0 + tx] = f2b(t[tx][ty + r]);
}

// ---------------- LayerNorm (Annotated-Transformer variant: g*(x-mu)/(sd+eps)+b, unbiased std)
template<int OUTB>
__global__ __launch_bounds__(64)
void ln_kernel(const float* __restrict__ x, const float* __restrict__ g, const float* __restrict__ b,
               ushort* __restrict__ ob, float* __restrict__ of){
  int row = blockIdx.x, lane = threadIdx.x;
  float4 v = ((const float4*)(x + (long)row * D_))[lane];
  float s = v.x + v.y + v.z + v.w;
  float s2 = v.x*v.x + v.y*v.y + v.z*v.z + v.w*v.w;
  #pragma unroll
  for (int o = 32; o; o >>= 1){ s += __shfl_xor(s, o); s2 += __shfl_xor(s2, o); }
  float mu = s * (1.f / D_);
  float var = (s2 - D_ * mu * mu) * (1.f / (D_ - 1));
  var = fmaxf(var, 0.f);
  float inv = 1.f / (sqrtf(var) + 1e-6f);
  float4 gv = ((const float4*)g)[lane];
  float4 bv = ((const float4*)b)[lane];
  float o0 = gv.x * (v.x - mu) * inv + bv.x;
  float o1 = gv.y * (v.y - mu) * inv + bv.y;
  float o2 = gv.z * (v.z - mu) * inv + bv.z;
  float o3 = gv.w * (v.w - mu) * inv + bv.w;
  if (OUTB){
    ushort4 u; u.x = f2b(o0); u.y = f2b(o1); u.z = f2b(o2); u.w = f2b(o3);
    ((ushort4*)ob)[(long)row * 64 + lane] = u;
  } else {
    float4 o; o.x = o0; o.y = o1; o.z = o2; o.w = o3;
    ((float4*)of)[(long)row * 64 + lane] = o;
  }
}

// ---------------- bf16 MFMA GEMM: out[M][Nc] = A[M][K] @ WT[Nc][K]^T + bias (+resid, relu)
// QKV mode: Nc=768, three weight/bias pointers selected by column block of 256.
template<int QKV, int RELU, int RESID, int OUTF, int OUTB>
__global__ __launch_bounds__(256)
void gemm_kernel(const ushort* __restrict__ A,
                 const ushort* __restrict__ W0, const ushort* __restrict__ W1p, const ushort* __restrict__ W2p,
                 const float* __restrict__ B0, const float* __restrict__ B1p, const float* __restrict__ B2p,
                 float* __restrict__ resid, float* __restrict__ outF, ushort* __restrict__ outB,
                 int M, int Nc, int K){
  __shared__ ushort Al[64 * 48];
  __shared__ ushort Bl[64 * 48];
  int tid = threadIdx.x;
  int lane = tid & 63, w = tid >> 6;
  int wm = w >> 1, wn = w & 1;
  int bn0 = blockIdx.x * 64, bm0 = blockIdx.y * 64;
  const ushort* WT; const float* bias; int wn0;
  if (QKV){
    int which = bn0 >> 8;
    WT = which == 0 ? W0 : (which == 1 ? W1p : W2p);
    bias = which == 0 ? B0 : (which == 1 ? B1p : B2p);
    wn0 = bn0 & 255;
  } else { WT = W0; bias = B0; wn0 = bn0; }

  int r4 = tid >> 2, c8 = (tid & 3) * 8;
  const ushort* ag = A + (long)(bm0 + r4) * K + c8;
  const ushort* bg = WT + (long)(wn0 + r4) * K + c8;

  f4v acc[2][2];
  #pragma unroll
  for (int i = 0; i < 2; ++i)
    #pragma unroll
    for (int j = 0; j < 2; ++j)
      acc[i][j] = (f4v){0.f, 0.f, 0.f, 0.f};

  int l16 = lane & 15, lg = lane >> 4;
  int arow0 = (wm * 32 + l16) * 48 + lg * 8;
  int brow0 = (wn * 32 + l16) * 48 + lg * 8;

  for (int k0 = 0; k0 < K; k0 += 32){
    b8v a8 = *(const b8v*)(ag + k0);
    b8v b8 = *(const b8v*)(bg + k0);
    __syncthreads();
    *(b8v*)&Al[r4 * 48 + c8] = a8;
    *(b8v*)&Bl[r4 * 48 + c8] = b8;
    __syncthreads();
    b8v a0 = *(const b8v*)&Al[arow0];
    b8v a1 = *(const b8v*)&Al[arow0 + 16 * 48];
    b8v b0 = *(const b8v*)&Bl[brow0];
    b8v b1 = *(const b8v*)&Bl[brow0 + 16 * 48];
    acc[0][0] = __builtin_amdgcn_mfma_f32_16x16x32_bf16(a0, b0, acc[0][0], 0, 0, 0);
    acc[0][1] = __builtin_amdgcn_mfma_f32_16x16x32_bf16(a0, b1, acc[0][1], 0, 0, 0);
    acc[1][0] = __builtin_amdgcn_mfma_f32_16x16x32_bf16(a1, b0, acc[1][0], 0, 0, 0);
    acc[1][1] = __builtin_amdgcn_mfma_f32_16x16x32_bf16(a1, b1, acc[1][1], 0, 0, 0);
  }
  #pragma unroll
  for (int fi = 0; fi < 2; ++fi)
    #pragma unroll
    for (int fj = 0; fj < 2; ++fj)
      #pragma unroll
      for (int j = 0; j < 4; ++j){
        int row = bm0 + wm * 32 + fi * 16 + lg * 4 + j;
        int col = bn0 + wn * 32 + fj * 16 + l16;
        float v = acc[fi][fj][j] + bias[QKV ? (col & 255) : col];
        if (RELU) v = fmaxf(v, 0.f);
        long idx = (long)row * Nc + col;
        if (RESID) v += resid[idx];
        if (OUTF) outF[idx] = v;
        if (OUTB) outB[idx] = f2b(v);
      }
}

// ---------------- qr[h][i][r] = scale * q[i,h*32:+32] . rel_k_emb[r]
__global__ __launch_bounds__(320)
void qr_kernel(const float* __restrict__ qall, const float* __restrict__ rke, float* __restrict__ qr){
  __shared__ float ql[D_];
  int i = blockIdx.x, t = threadIdx.x;
  if (t < D_) ql[t] = qall[(long)i * 768 + t];
  __syncthreads();
  if (t < H_ * R_){
    int h = t / R_, r = t % R_;
    const float* qh = &ql[h * DK_];
    const float* e = rke + r * DK_;
    float acc = 0.f;
    #pragma unroll
    for (int d = 0; d < DK_; ++d) acc += qh[d] * e[d];
    qr[((long)h * N_ + i) * R_ + r] = acc * 0.17677669529663689f;
  }
}

// ---------------- flash attention partial (j-split) with relation bias + relation bins
__global__ __launch_bounds__(256)
void attn_kernel(const float* __restrict__ qall, const float* __restrict__ qr,
                 const int* __restrict__ rel, float* __restrict__ part){
  __shared__ float q_l[IB_ * 36];
  __shared__ float k_l[64 * 32];
  __shared__ float v_l[64 * 36];
  __shared__ float o1[IB_ * 32];
  __shared__ float prb[IB_ * 40];
  __shared__ float p_l[4 * 64];
  __shared__ float mrow[IB_], lrow[IB_];

  int tid = threadIdx.x, lane = tid & 63, w = tid >> 6;
  int ib0 = blockIdx.x * IB_, h = blockIdx.y, js = blockIdx.z;

  for (int idx = tid; idx < IB_ * 32; idx += 256) o1[idx] = 0.f;
  for (int idx = tid; idx < IB_ * 40; idx += 256) prb[idx] = 0.f;
  if (tid < IB_){ mrow[tid] = -3.0e38f; lrow[tid] = 0.f; }
  {
    int r = tid >> 3, d0 = (tid & 7) * 4;
    float4 qv = *(const float4*)(qall + (long)(ib0 + r) * 768 + h * 32 + d0);
    const float sc = 0.17677669529663689f;
    qv.x *= sc; qv.y *= sc; qv.z *= sc; qv.w *= sc;
    *(float4*)&q_l[r * 36 + d0] = qv;
  }
  __syncthreads();

  int d = lane & 31, half = lane >> 5;
  float kreg[32];

  for (int jt = 0; jt < 4; ++jt){
    int j0 = js * 256 + jt * 64;
    __syncthreads();
    {
      int r = tid >> 2, d0 = (tid & 3) * 8;
      const float* kp = qall + (long)(j0 + r) * 768 + 256 + h * 32 + d0;
      const float* vp = qall + (long)(j0 + r) * 768 + 512 + h * 32 + d0;
      float4 k0v = *(const float4*)kp;
      float4 k1v = *(const float4*)(kp + 4);
      int ch0 = ((d0 >> 2) ^ (r & 7)) * 4;
      int ch1 = (((d0 >> 2) + 1) ^ (r & 7)) * 4;
      *(float4*)&k_l[r * 32 + ch0] = k0v;
      *(float4*)&k_l[r * 32 + ch1] = k1v;
      *(float4*)&v_l[r * 36 + d0] = *(const float4*)vp;
      *(float4*)&v_l[r * 36 + d0 + 4] = *(const float4*)(vp + 4);
    }
    __syncthreads();
    #pragma unroll
    for (int c = 0; c < 8; ++c){
      int pos = (c ^ (lane & 7)) * 4;
      float4 kv = *(const float4*)&k_l[lane * 32 + pos];
      kreg[c * 4 + 0] = kv.x; kreg[c * 4 + 1] = kv.y;
      kreg[c * 4 + 2] = kv.z; kreg[c * 4 + 3] = kv.w;
    }
    for (int ir = 0; ir < 8; ++ir){
      int gi = w * 8 + ir;
      int gir = ib0 + gi;
      float s = 0.f;
      #pragma unroll
      for (int c = 0; c < 8; ++c){
        float4 qv = *(const float4*)&q_l[gi * 36 + c * 4];
        s += qv.x * kreg[c * 4] + qv.y * kreg[c * 4 + 1] + qv.z * kreg[c * 4 + 2] + qv.w * kreg[c * 4 + 3];
      }
      int rix = rel[(long)gir * N_ + j0 + lane];
      s += qr[((long)h * N_ + gir) * R_ + rix];

      float tm = wred_max(s);
      float mo = mrow[gi];
      float mu;
      if (tm > mo){
        float f = __expf(mo - tm);
        if (lane < 32) o1[gi * 32 + lane] *= f;
        if (lane < R_) prb[gi * 40 + lane] *= f;
        if (lane == 0){ lrow[gi] *= f; mrow[gi] = tm; }
        mu = tm;
      } else mu = mo;
      float p = __expf(s - mu);
      float ts = wred_sum(p);
      if (lane == 0) lrow[gi] += ts;
      p_l[w * 64 + lane] = p;
      atomicAdd(&prb[gi * 40 + rix], p);
      float partl = 0.f;
      #pragma unroll
      for (int t2 = 0; t2 < 32; ++t2){
        int j = half * 32 + t2;
        partl += p_l[w * 64 + j] * v_l[j * 36 + d];
      }
      partl += __shfl_xor(partl, 32);
      if (lane < 32) o1[gi * 32 + d] += partl;
    }
  }
  float* pb = part + (((long)h * JS_ + js) * N_) * 72;
  for (int ir = 0; ir < 8; ++ir){
    int gi = w * 8 + ir;
    float* pp = pb + (long)(ib0 + gi) * 72;
    if (lane < 32) pp[lane] = o1[gi * 32 + lane];
    if (lane < R_) pp[32 + lane] = prb[gi * 40 + lane];
    if (lane == 0){ pp[69] = mrow[gi]; pp[70] = lrow[gi]; }
  }
}

// ---------------- combine j-split partials, add pr@rel_v_emb, normalize, emit bf16
__global__ __launch_bounds__(256)
void combine_kernel(const float* __restrict__ part, const float* __restrict__ rve,
                    ushort* __restrict__ ob){
  __shared__ float prl[4][40];
  int tid = threadIdx.x, lane = tid & 63, w = tid >> 6;
  int i = blockIdx.x * 4 + w, h = blockIdx.y;
  int d = lane & 31;
  const float* pb = part + ((long)h * JS_) * N_ * 72 + (long)i * 72;
  float ms[JS_], ls[JS_], wf[JS_];
  float mstar = -3.0e38f;
  #pragma unroll
  for (int s = 0; s < JS_; ++s){
    ms[s] = pb[(long)s * N_ * 72 + 69];
    ls[s] = pb[(long)s * N_ * 72 + 70];
    mstar = fmaxf(mstar, ms[s]);
  }
  float lstar = 0.f;
  #pragma unroll
  for (int s = 0; s < JS_; ++s){ wf[s] = __expf(ms[s] - mstar); lstar += ls[s] * wf[s]; }
  float o1d = 0.f;
  #pragma unroll
  for (int s = 0; s < JS_; ++s) o1d += pb[(long)s * N_ * 72 + d] * wf[s];
  if (lane < R_){
    float prv = 0.f;
    #pragma unroll
    for (int s = 0; s < JS_; ++s) prv += pb[(long)s * N_ * 72 + 32 + lane] * wf[s];
    prl[w][lane] = prv;
  }
  float o2 = 0.f;
  for (int r = 0; r < R_; ++r) o2 += prl[w][r] * rve[r * DK_ + d];
  float val = (o1d + o2) / lstar;
  if (lane < 32) ob[(long)i * D_ + h * DK_ + d] = f2b(val);
}

extern "C" void kernel_launch(void* const* d_in, const int* in_sizes, int n_in,
                              void* d_out, int out_size, void* d_ws, size_t ws_size,
                              hipStream_t stream){
  const float* x    = (const float*)d_in[0];
  const int*   rel  = (const int*)d_in[1];
  const float* Wq   = (const float*)d_in[2];
  const float* bq   = (const float*)d_in[3];
  const float* Wk   = (const float*)d_in[4];
  const float* bk   = (const float*)d_in[5];
  const float* Wv   = (const float*)d_in[6];
  const float* bv   = (const float*)d_in[7];
  const float* Wo   = (const float*)d_in[8];
  const float* bo   = (const float*)d_in[9];
  const float* rke  = (const float*)d_in[10];
  const float* rve  = (const float*)d_in[11];
  const float* W1   = (const float*)d_in[12];
  const float* b1   = (const float*)d_in[13];
  const float* W2   = (const float*)d_in[14];
  const float* b2   = (const float*)d_in[15];
  const float* ln1g = (const float*)d_in[16];
  const float* ln1b = (const float*)d_in[17];
  const float* ln2g = (const float*)d_in[18];
  const float* ln2b = (const float*)d_in[19];
  const float* lnfg = (const float*)d_in[20];
  const float* lnfb = (const float*)d_in[21];

  char* wsb = (char*)d_ws;
  size_t off = 0;
  auto alloc = [&](size_t bytes){ void* p = wsb + off; off += (bytes + 255) & ~255ull; return p; };
  float*  xw   = (float*) alloc((size_t)N_ * D_ * 4);
  float*  qall = (float*) alloc((size_t)N_ * 768 * 4);
  float*  qr   = (float*) alloc((size_t)H_ * N_ * R_ * 4);
  ushort* xnb  = (ushort*)alloc((size_t)N_ * D_ * 2);
  ushort* obf  = (ushort*)alloc((size_t)N_ * D_ * 2);
  float*  part = (float*) alloc((size_t)H_ * JS_ * N_ * 72 * 4);
  ushort* hidb = (ushort*)part;  // alias: part dead during FFN, rewritten next layer
  ushort* wqT  = (ushort*)alloc((size_t)L_ * D_ * D_ * 2);
  ushort* wkT  = (ushort*)alloc((size_t)L_ * D_ * D_ * 2);
  ushort* wvT  = (ushort*)alloc((size_t)L_ * D_ * D_ * 2);
  ushort* woT  = (ushort*)alloc((size_t)L_ * D_ * D_ * 2);
  ushort* w1T  = (ushort*)alloc((size_t)L_ * D_ * FF_ * 2);
  ushort* w2T  = (ushort*)alloc((size_t)L_ * D_ * FF_ * 2);
  (void)ws_size; (void)in_sizes; (void)n_in; (void)out_size;

  dim3 tb(32, 8);
  wcast_kernel<<<dim3(D_/32,  D_/32,  L_), tb, 0, stream>>>(Wq, wqT, D_, D_);
  wcast_kernel<<<dim3(D_/32,  D_/32,  L_), tb, 0, stream>>>(Wk, wkT, D_, D_);
  wcast_kernel<<<dim3(D_/32,  D_/32,  L_), tb, 0, stream>>>(Wv, wvT, D_, D_);
  wcast_kernel<<<dim3(D_/32,  D_/32,  L_), tb, 0, stream>>>(Wo, woT, D_, D_);
  wcast_kernel<<<dim3(FF_/32, D_/32,  L_), tb, 0, stream>>>(W1, w1T, D_, FF_);
  wcast_kernel<<<dim3(D_/32,  FF_/32, L_), tb, 0, stream>>>(W2, w2T, FF_, D_);

  hipMemcpyAsync(xw, x, (size_t)N_ * D_ * 4, hipMemcpyDeviceToDevice, stream);

  for (int l = 0; l < L_; ++l){
    ln_kernel<1><<<N_, 64, 0, stream>>>(xw, ln1g + l * D_, ln1b + l * D_, xnb, nullptr);
    gemm_kernel<1,0,0,1,0><<<dim3(768/64, N_/64), 256, 0, stream>>>(
        xnb, wqT + (size_t)l * D_ * D_, wkT + (size_t)l * D_ * D_, wvT + (size_t)l * D_ * D_,
        bq + l * D_, bk + l * D_, bv + l * D_,
        nullptr, qall, nullptr, N_, 768, D_);
    qr_kernel<<<N_, 320, 0, stream>>>(qall, rke + (size_t)l * R_ * DK_, qr);
    attn_kernel<<<dim3(N_/IB_, H_, JS_), 256, 0, stream>>>(qall, qr, rel, part);
    combine_kernel<<<dim3(N_/4, H_), 256, 0, stream>>>(part, rve + (size_t)l * R_ * DK_, obf);
    gemm_kernel<0,0,1,1,0><<<dim3(D_/64, N_/64), 256, 0, stream>>>(
        obf, woT + (size_t)l * D_ * D_, nullptr, nullptr,
        bo + l * D_, nullptr, nullptr,
        xw, xw, nullptr, N_, D_, D_);
    ln_kernel<1><<<N_, 64, 0, stream>>>(xw, ln2g + l * D_, ln2b + l * D_, xnb, nullptr);
    gemm_kernel<0,1,0,0,1><<<dim3(FF_/64, N_/64), 256, 0, stream>>>(
        xnb, w1T + (size_t)l * D_ * FF_, nullptr, nullptr,
        b1 + l * FF_, nullptr, nullptr,
        nullptr, nullptr, hidb, N_, FF_, D_);
    gemm_kernel<0,0,1,1,0><<<dim3(D_/64, N_/64), 256, 0, stream>>>(
        hidb, w2T + (size_t)l * FF_ * D_, nullptr, nullptr,
        b2 + l * D_, nullptr, nullptr,
        xw, xw, nullptr, N_, D_, FF_);
  }
  ln_kernel<0><<<N_, 64, 0, stream>>>(xw, lnfg, lnfb, nullptr, (float*)d_out);
}

// Round 2
// 931.488 us; speedup vs baseline: 1.5257x; 1.5257x over previous
//
#include <hip/hip_runtime.h>
#include <stdint.h>

#define L_ 8
#define D_ 256
#define H_ 8
#define DK_ 32
#define FF_ 1024
#define R_ 37
#define N_ 1024
#define JS_ 4

// scale * log2(e): attention runs in exp2 domain
#define SCL (0.17677669529663689f * 1.4426950408889634f)

typedef float f4v __attribute__((ext_vector_type(4)));
typedef short b8v __attribute__((ext_vector_type(8)));
typedef uint  u2v __attribute__((ext_vector_type(2)));

__device__ __forceinline__ ushort f2b(float f){
  union { float f; uint32_t u; } x; x.f = f;
  return (ushort)((x.u + 0x7FFFu + ((x.u >> 16) & 1u)) >> 16);
}
__device__ __forceinline__ float b2f(ushort u){
  union { uint32_t u; float f; } x; x.u = ((uint32_t)u) << 16;
  return x.f;
}
__device__ __forceinline__ uint pk2b(float lo, float hi){
  return (((uint)f2b(hi)) << 16) | (uint)f2b(lo);
}
__device__ __forceinline__ float ex2(float x){ return __builtin_amdgcn_exp2f(x); }

// ---------------- weight transpose + cast: src [L][K][Nc] f32 -> dst [L][Nc][K] bf16
__global__ __launch_bounds__(256)
void wcast_kernel(const float* __restrict__ src, ushort* __restrict__ dst, int K, int Nc){
  __shared__ float t[32][33];
  int l = blockIdx.z;
  long base = (long)l * K * Nc;
  int n0 = blockIdx.x * 32, k0 = blockIdx.y * 32;
  int tx = threadIdx.x, ty = threadIdx.y; // (32,8)
  #pragma unroll
  for (int r = 0; r < 32; r += 8)
    t[ty + r][tx] = src[base + (long)(k0 + ty + r) * Nc + n0 + tx];
  __syncthreads();
  #pragma unroll
  for (int r = 0; r < 32; r += 8)
    dst[base + (long)(n0 + ty + r) * K + k0 + tx] = f2b(t[tx][ty + r]);
}

// ---------------- LayerNorm
template<int OUTB>
__global__ __launch_bounds__(64)
void ln_kernel(const float* __restrict__ x, const float* __restrict__ g, const float* __restrict__ b,
               ushort* __restrict__ ob, float* __restrict__ of){
  int row = blockIdx.x, lane = threadIdx.x;
  float4 v = ((const float4*)(x + (long)row * D_))[lane];
  float s = v.x + v.y + v.z + v.w;
  float s2 = v.x*v.x + v.y*v.y + v.z*v.z + v.w*v.w;
  #pragma unroll
  for (int o = 32; o; o >>= 1){ s += __shfl_xor(s, o); s2 += __shfl_xor(s2, o); }
  float mu = s * (1.f / D_);
  float var = (s2 - D_ * mu * mu) * (1.f / (D_ - 1));
  var = fmaxf(var, 0.f);
  float inv = 1.f / (sqrtf(var) + 1e-6f);
  float4 gv = ((const float4*)g)[lane];
  float4 bv = ((const float4*)b)[lane];
  float o0 = gv.x * (v.x - mu) * inv + bv.x;
  float o1 = gv.y * (v.y - mu) * inv + bv.y;
  float o2 = gv.z * (v.z - mu) * inv + bv.z;
  float o3 = gv.w * (v.w - mu) * inv + bv.w;
  if (OUTB){
    ushort4 u; u.x = f2b(o0); u.y = f2b(o1); u.z = f2b(o2); u.w = f2b(o3);
    ((ushort4*)ob)[(long)row * 64 + lane] = u;
  } else {
    float4 o; o.x = o0; o.y = o1; o.z = o2; o.w = o3;
    ((float4*)of)[(long)row * 64 + lane] = o;
  }
}

// ---------------- bf16 MFMA GEMM. QKV mode writes head-split bf16 q/k/v to outB.
template<int QKV, int RELU, int RESID, int OUTF, int OUTB>
__global__ __launch_bounds__(256)
void gemm_kernel(const ushort* __restrict__ A,
                 const ushort* __restrict__ W0, const ushort* __restrict__ W1p, const ushort* __restrict__ W2p,
                 const float* __restrict__ B0, const float* __restrict__ B1p, const float* __restrict__ B2p,
                 float* __restrict__ resid, float* __restrict__ outF, ushort* __restrict__ outB,
                 int M, int Nc, int K){
  __shared__ ushort Al[64 * 48];
  __shared__ ushort Bl[64 * 48];
  int tid = threadIdx.x;
  int lane = tid & 63, w = tid >> 6;
  int wm = w >> 1, wn = w & 1;
  int bn0 = blockIdx.x * 64, bm0 = blockIdx.y * 64;
  const ushort* WT; const float* bias; int wn0;
  if (QKV){
    int which = bn0 >> 8;
    WT = which == 0 ? W0 : (which == 1 ? W1p : W2p);
    bias = which == 0 ? B0 : (which == 1 ? B1p : B2p);
    wn0 = bn0 & 255;
  } else { WT = W0; bias = B0; wn0 = bn0; }

  int r4 = tid >> 2, c8 = (tid & 3) * 8;
  const ushort* ag = A + (long)(bm0 + r4) * K + c8;
  const ushort* bg = WT + (long)(wn0 + r4) * K + c8;

  f4v acc[2][2];
  #pragma unroll
  for (int i = 0; i < 2; ++i)
    #pragma unroll
    for (int j = 0; j < 2; ++j)
      acc[i][j] = (f4v){0.f, 0.f, 0.f, 0.f};

  int l16 = lane & 15, lg = lane >> 4;
  int arow0 = (wm * 32 + l16) * 48 + lg * 8;
  int brow0 = (wn * 32 + l16) * 48 + lg * 8;

  for (int k0 = 0; k0 < K; k0 += 32){
    b8v a8 = *(const b8v*)(ag + k0);
    b8v b8 = *(const b8v*)(bg + k0);
    __syncthreads();
    *(b8v*)&Al[r4 * 48 + c8] = a8;
    *(b8v*)&Bl[r4 * 48 + c8] = b8;
    __syncthreads();
    b8v a0 = *(const b8v*)&Al[arow0];
    b8v a1 = *(const b8v*)&Al[arow0 + 16 * 48];
    b8v b0 = *(const b8v*)&Bl[brow0];
    b8v b1 = *(const b8v*)&Bl[brow0 + 16 * 48];
    acc[0][0] = __builtin_amdgcn_mfma_f32_16x16x32_bf16(a0, b0, acc[0][0], 0, 0, 0);
    acc[0][1] = __builtin_amdgcn_mfma_f32_16x16x32_bf16(a0, b1, acc[0][1], 0, 0, 0);
    acc[1][0] = __builtin_amdgcn_mfma_f32_16x16x32_bf16(a1, b0, acc[1][0], 0, 0, 0);
    acc[1][1] = __builtin_amdgcn_mfma_f32_16x16x32_bf16(a1, b1, acc[1][1], 0, 0, 0);
  }
  #pragma unroll
  for (int fi = 0; fi < 2; ++fi)
    #pragma unroll
    for (int fj = 0; fj < 2; ++fj)
      #pragma unroll
      for (int j = 0; j < 4; ++j){
        int row = bm0 + wm * 32 + fi * 16 + lg * 4 + j;
        int col = bn0 + wn * 32 + fj * 16 + l16;
        float v = acc[fi][fj][j] + bias[QKV ? (col & 255) : col];
        if (QKV){
          // head-split: [which][h][row][dk] bf16
          long idx = (long)(col >> 8) * 262144 + (long)(((col >> 5) & 7) << 15) + (row << 5) + (col & 31);
          outB[idx] = f2b(v);
        } else {
          if (RELU) v = fmaxf(v, 0.f);
          long idx = (long)row * Nc + col;
          if (RESID) v += resid[idx];
          if (OUTF) outF[idx] = v;
          if (OUTB) outB[idx] = f2b(v);
        }
      }
}

// ---------------- V transpose: vb[h][j][dk] -> vbt[h][dk][j]  (bf16)
__global__ __launch_bounds__(256)
void vt_kernel(const ushort* __restrict__ vb, ushort* __restrict__ vbt){
  __shared__ ushort t[64][36];
  int j0 = blockIdx.x * 64, h = blockIdx.y;
  int tid = threadIdx.x;
  {
    int r = tid >> 2, c = (tid & 3) * 8;
    *(b8v*)&t[r][c] = *(const b8v*)(vb + ((long)(h << 10) + j0 + r) * 32 + c);
  }
  __syncthreads();
  int d = tid >> 3, jj = (tid & 7) * 8;
  b8v o;
  #pragma unroll
  for (int e = 0; e < 8; ++e) o[e] = (short)t[jj + e][d];
  *(b8v*)(vbt + (long)(h * 32 + d) * 1024 + j0 + jj) = o;
}

// ---------------- qr[h][i][r] (padded to 40) = SCL * q[h,i,:] . rel_k_emb[r]
__global__ __launch_bounds__(320)
void qr_kernel(const ushort* __restrict__ qb, const float* __restrict__ rke, float* __restrict__ qr){
  __shared__ float ql[256];
  int i = blockIdx.x, t = threadIdx.x;
  if (t < 256){
    int h = t >> 5, dk = t & 31;
    ql[t] = b2f(qb[(long)((h << 10) + i) * 32 + dk]);
  }
  __syncthreads();
  if (t < H_ * R_){
    int h = t / R_, r = t - h * R_;
    const float* qh = &ql[h * DK_];
    const float* e = rke + r * DK_;
    float acc = 0.f;
    #pragma unroll
    for (int d = 0; d < DK_; ++d) acc += qh[d] * e[d];
    qr[((long)(h << 10) + i) * 40 + r] = acc * SCL;
  }
}

// ---------------- MFMA flash attention partial (j-split) with relation bias + bins
__global__ __launch_bounds__(256)
void attn_kernel(const ushort* __restrict__ qb, const ushort* __restrict__ kb,
                 const ushort* __restrict__ vbt, const float* __restrict__ qr,
                 const int* __restrict__ rel, float* __restrict__ part){
  __shared__ ushort q_l[64 * 40];
  __shared__ ushort k_l[32 * 40];
  __shared__ ushort vt_l[32 * 40];
  __shared__ int    rel_l[64 * 36];
  __shared__ float  qr_l[64 * 40];
  __shared__ float  prb[64 * 40];
  __shared__ uint   p_l[4 * 16 * 20];

  int tid = threadIdx.x, lane = tid & 63, w = tid >> 6;
  int l16 = lane & 15, g = lane >> 4;
  int ib0 = blockIdx.x * 64, h = blockIdx.y, js = blockIdx.z;
  int i_loc = w * 16 + l16;

  { // stage Q tile (64 x 32 bf16)
    int r = tid >> 2, c8 = (tid & 3) * 8;
    *(b8v*)&q_l[r * 40 + c8] = *(const b8v*)(qb + (long)((h << 10) + ib0 + r) * 32 + c8);
  }
  { // stage qr tile (64 x 40 f32) + zero bins
    const float* src = qr + (long)((h << 10) + ib0) * 40;
    for (int idx = tid; idx < 2560; idx += 256){ qr_l[idx] = src[idx]; prb[idx] = 0.f; }
  }
  __syncthreads();

  b8v qf = *(const b8v*)&q_l[i_loc * 40 + g * 8];

  f4v oacc0 = (f4v){0.f,0.f,0.f,0.f}, oacc1 = (f4v){0.f,0.f,0.f,0.f};
  float m = -3.0e38f, lsum = 0.f;
  const float* qrr = &qr_l[i_loc * 40];

  for (int jt = 0; jt < 8; ++jt){
    int j0 = js * 256 + jt * 32;
    __syncthreads();
    if (tid < 128){ // K tile (32 x 32)
      int r = tid >> 2, c8 = (tid & 3) * 8;
      *(b8v*)&k_l[r * 40 + c8] = *(const b8v*)(kb + (long)((h << 10) + j0 + r) * 32 + c8);
    } else {        // V^T tile (32 d x 32 j)
      int t2 = tid - 128;
      int d0 = t2 >> 2, c8 = (t2 & 3) * 8;
      *(b8v*)&vt_l[d0 * 40 + c8] = *(const b8v*)(vbt + (long)(h * 32 + d0) * 1024 + j0 + c8);
    }
    { // rel tile (64 x 32 int)
      int r = tid >> 3, c = (tid & 7) * 4;
      *(int4*)&rel_l[r * 36 + c] = *(const int4*)(rel + (long)(ib0 + r) * N_ + j0 + c);
      *(int4*)&rel_l[(r + 32) * 36 + c] = *(const int4*)(rel + (long)(ib0 + r + 32) * N_ + j0 + c);
    }
    __syncthreads();

    b8v kf0 = *(const b8v*)&k_l[l16 * 40 + g * 8];
    b8v kf1 = *(const b8v*)&k_l[(16 + l16) * 40 + g * 8];
    f4v z = (f4v){0.f,0.f,0.f,0.f};
    f4v s0 = __builtin_amdgcn_mfma_f32_16x16x32_bf16(kf0, qf, z, 0, 0, 0);
    f4v s1 = __builtin_amdgcn_mfma_f32_16x16x32_bf16(kf1, qf, z, 0, 0, 0);

    int4 r0 = *(const int4*)&rel_l[i_loc * 36 + g * 4];
    int4 r1 = *(const int4*)&rel_l[i_loc * 36 + 16 + g * 4];
    int rix[8] = { r0.x, r0.y, r0.z, r0.w, r1.x, r1.y, r1.z, r1.w };
    float sv[8];
    #pragma unroll
    for (int e = 0; e < 4; ++e){
      sv[e]     = s0[e] * SCL + qrr[rix[e]];
      sv[e + 4] = s1[e] * SCL + qrr[rix[e + 4]];
    }
    float tmax = sv[0];
    #pragma unroll
    for (int e = 1; e < 8; ++e) tmax = fmaxf(tmax, sv[e]);
    tmax = fmaxf(tmax, __shfl_xor(tmax, 16));
    tmax = fmaxf(tmax, __shfl_xor(tmax, 32));
    float mn = fmaxf(m, tmax);
    float f = ex2(m - mn);
    float p[8]; float ps = 0.f;
    #pragma unroll
    for (int e = 0; e < 8; ++e){ p[e] = ex2(sv[e] - mn); ps += p[e]; }
    ps += __shfl_xor(ps, 16);
    ps += __shfl_xor(ps, 32);
    lsum = lsum * f + ps;
    oacc0 *= f; oacc1 *= f;
    if (mn > m){
      #pragma unroll
      for (int b2 = 0; b2 < 10; ++b2){
        int bi = g * 10 + b2;
        if (bi < R_) prb[i_loc * 40 + bi] *= f;
      }
    }
    m = mn;
    #pragma unroll
    for (int e = 0; e < 8; ++e) atomicAdd(&prb[i_loc * 40 + rix[e]], p[e]);

    // repack P^T to bf16 A..B fragment via wave-private LDS
    uint pk0 = pk2b(p[0], p[1]), pk1 = pk2b(p[2], p[3]);
    uint pk2 = pk2b(p[4], p[5]), pk3 = pk2b(p[6], p[7]);
    uint* pw = &p_l[w * 320 + l16 * 20];
    *(u2v*)&pw[g * 2]     = (u2v){pk0, pk1};
    *(u2v*)&pw[8 + g * 2] = (u2v){pk2, pk3};
    b8v pf = *(const b8v*)&pw[g * 4];
    b8v vt0 = *(const b8v*)&vt_l[l16 * 40 + g * 8];
    b8v vt1 = *(const b8v*)&vt_l[(16 + l16) * 40 + g * 8];
    oacc0 = __builtin_amdgcn_mfma_f32_16x16x32_bf16(vt0, pf, oacc0, 0, 0, 0);
    oacc1 = __builtin_amdgcn_mfma_f32_16x16x32_bf16(vt1, pf, oacc1, 0, 0, 0);
  }

  float* pp = part + ((long)(h * JS_ + js) * N_ + ib0 + i_loc) * 72;
  #pragma unroll
  for (int r2 = 0; r2 < 4; ++r2){
    pp[g * 4 + r2] = oacc0[r2];
    pp[16 + g * 4 + r2] = oacc1[r2];
  }
  #pragma unroll
  for (int b2 = 0; b2 < 10; ++b2){
    int bi = g * 10 + b2;
    if (bi < R_) pp[32 + bi] = prb[i_loc * 40 + bi];
  }
  if (g == 0){ pp[69] = m; pp[70] = lsum; }
}

// ---------------- combine j-split partials, add pr@rel_v_emb, normalize, emit bf16
__global__ __launch_bounds__(256)
void combine_kernel(const float* __restrict__ part, const float* __restrict__ rve,
                    ushort* __restrict__ ob){
  __shared__ float prl[4][40];
  int tid = threadIdx.x, lane = tid & 63, w = tid >> 6;
  int i = blockIdx.x * 4 + w, h = blockIdx.y;
  int d = lane & 31;
  const float* pb = part + ((long)h * JS_) * N_ * 72 + (long)i * 72;
  float ms[JS_], ls[JS_], wf[JS_];
  float mstar = -3.0e38f;
  #pragma unroll
  for (int s = 0; s < JS_; ++s){
    ms[s] = pb[(long)s * N_ * 72 + 69];
    ls[s] = pb[(long)s * N_ * 72 + 70];
    mstar = fmaxf(mstar, ms[s]);
  }
  float lstar = 0.f;
  #pragma unroll
  for (int s = 0; s < JS_; ++s){ wf[s] = ex2(ms[s] - mstar); lstar += ls[s] * wf[s]; }
  float o1d = 0.f;
  #pragma unroll
  for (int s = 0; s < JS_; ++s) o1d += pb[(long)s * N_ * 72 + d] * wf[s];
  if (lane < R_){
    float prv = 0.f;
    #pragma unroll
    for (int s = 0; s < JS_; ++s) prv += pb[(long)s * N_ * 72 + 32 + lane] * wf[s];
    prl[w][lane] = prv;
  }
  float o2 = 0.f;
  for (int r = 0; r < R_; ++r) o2 += prl[w][r] * rve[r * DK_ + d];
  float val = (o1d + o2) / lstar;
  if (lane < 32) ob[(long)i * D_ + h * DK_ + d] = f2b(val);
}

extern "C" void kernel_launch(void* const* d_in, const int* in_sizes, int n_in,
                              void* d_out, int out_size, void* d_ws, size_t ws_size,
                              hipStream_t stream){
  const float* x    = (const float*)d_in[0];
  const int*   rel  = (const int*)d_in[1];
  const float* Wq   = (const float*)d_in[2];
  const float* bq   = (const float*)d_in[3];
  const float* Wk   = (const float*)d_in[4];
  const float* bk   = (const float*)d_in[5];
  const float* Wv   = (const float*)d_in[6];
  const float* bv   = (const float*)d_in[7];
  const float* Wo   = (const float*)d_in[8];
  const float* bo   = (const float*)d_in[9];
  const float* rke  = (const float*)d_in[10];
  const float* rve  = (const float*)d_in[11];
  const float* W1   = (const float*)d_in[12];
  const float* b1   = (const float*)d_in[13];
  const float* W2   = (const float*)d_in[14];
  const float* b2   = (const float*)d_in[15];
  const float* ln1g = (const float*)d_in[16];
  const float* ln1b = (const float*)d_in[17];
  const float* ln2g = (const float*)d_in[18];
  const float* ln2b = (const float*)d_in[19];
  const float* lnfg = (const float*)d_in[20];
  const float* lnfb = (const float*)d_in[21];

  char* wsb = (char*)d_ws;
  size_t off = 0;
  auto alloc = [&](size_t bytes){ void* p = wsb + off; off += (bytes + 255) & ~255ull; return p; };
  float*  xw   = (float*) alloc((size_t)N_ * D_ * 4);
  ushort* qkvb = (ushort*)alloc((size_t)3 * H_ * N_ * DK_ * 2);
  ushort* vbt  = (ushort*)alloc((size_t)H_ * DK_ * N_ * 2);
  float*  qr   = (float*) alloc((size_t)H_ * N_ * 40 * 4);
  ushort* xnb  = (ushort*)alloc((size_t)N_ * D_ * 2);
  ushort* obf  = (ushort*)alloc((size_t)N_ * D_ * 2);
  float*  part = (float*) alloc((size_t)H_ * JS_ * N_ * 72 * 4);
  ushort* hidb = (ushort*)part;  // alias: part dead during FFN
  ushort* wqT  = (ushort*)alloc((size_t)L_ * D_ * D_ * 2);
  ushort* wkT  = (ushort*)alloc((size_t)L_ * D_ * D_ * 2);
  ushort* wvT  = (ushort*)alloc((size_t)L_ * D_ * D_ * 2);
  ushort* woT  = (ushort*)alloc((size_t)L_ * D_ * D_ * 2);
  ushort* w1T  = (ushort*)alloc((size_t)L_ * D_ * FF_ * 2);
  ushort* w2T  = (ushort*)alloc((size_t)L_ * D_ * FF_ * 2);
  (void)ws_size; (void)in_sizes; (void)n_in; (void)out_size;

  ushort* qb = qkvb;
  ushort* kb = qkvb + (size_t)H_ * N_ * DK_;
  ushort* vb = qkvb + (size_t)2 * H_ * N_ * DK_;

  dim3 tb(32, 8);
  wcast_kernel<<<dim3(D_/32,  D_/32,  L_), tb, 0, stream>>>(Wq, wqT, D_, D_);
  wcast_kernel<<<dim3(D_/32,  D_/32,  L_), tb, 0, stream>>>(Wk, wkT, D_, D_);
  wcast_kernel<<<dim3(D_/32,  D_/32,  L_), tb, 0, stream>>>(Wv, wvT, D_, D_);
  wcast_kernel<<<dim3(D_/32,  D_/32,  L_), tb, 0, stream>>>(Wo, woT, D_, D_);
  wcast_kernel<<<dim3(FF_/32, D_/32,  L_), tb, 0, stream>>>(W1, w1T, D_, FF_);
  wcast_kernel<<<dim3(D_/32,  FF_/32, L_), tb, 0, stream>>>(W2, w2T, FF_, D_);

  hipMemcpyAsync(xw, x, (size_t)N_ * D_ * 4, hipMemcpyDeviceToDevice, stream);

  for (int l = 0; l < L_; ++l){
    ln_kernel<1><<<N_, 64, 0, stream>>>(xw, ln1g + l * D_, ln1b + l * D_, xnb, nullptr);
    gemm_kernel<1,0,0,0,1><<<dim3(768/64, N_/64), 256, 0, stream>>>(
        xnb, wqT + (size_t)l * D_ * D_, wkT + (size_t)l * D_ * D_, wvT + (size_t)l * D_ * D_,
        bq + l * D_, bk + l * D_, bv + l * D_,
        nullptr, nullptr, qkvb, N_, 768, D_);
    vt_kernel<<<dim3(N_/64, H_), 256, 0, stream>>>(vb, vbt);
    qr_kernel<<<N_, 320, 0, stream>>>(qb, rke + (size_t)l * R_ * DK_, qr);
    attn_kernel<<<dim3(N_/64, H_, JS_), 256, 0, stream>>>(qb, kb, vbt, qr, rel, part);
    combine_kernel<<<dim3(N_/4, H_), 256, 0, stream>>>(part, rve + (size_t)l * R_ * DK_, obf);
    gemm_kernel<0,0,1,1,0><<<dim3(D_/64, N_/64), 256, 0, stream>>>(
        obf, woT + (size_t)l * D_ * D_, nullptr, nullptr,
        bo + l * D_, nullptr, nullptr,
        xw, xw, nullptr, N_, D_, D_);
    ln_kernel<1><<<N_, 64, 0, stream>>>(xw, ln2g + l * D_, ln2b + l * D_, xnb, nullptr);
    gemm_kernel<0,1,0,0,1><<<dim3(FF_/64, N_/64), 256, 0, stream>>>(
        xnb, w1T + (size_t)l * D_ * FF_, nullptr, nullptr,
        b1 + l * FF_, nullptr, nullptr,
        nullptr, nullptr, hidb, N_, FF_, D_);
    gemm_kernel<0,0,1,1,0><<<dim3(D_/64, N_/64), 256, 0, stream>>>(
        hidb, w2T + (size_t)l * FF_ * D_, nullptr, nullptr,
        b2 + l * D_, nullptr, nullptr,
        xw, xw, nullptr, N_, D_, FF_);
  }
  ln_kernel<0><<<N_, 64, 0, stream>>>(xw, lnfg, lnfb, nullptr, (float*)d_out);
}

// Round 3
// 871.903 us; speedup vs baseline: 1.6299x; 1.0683x over previous
//
#include <hip/hip_runtime.h>
#include <stdint.h>

#define L_ 8
#define D_ 256
#define H_ 8
#define DK_ 32
#define FF_ 1024
#define R_ 37
#define N_ 1024
#define JS_ 8

// scale * log2(e): attention runs in exp2 domain
#define SCL (0.17677669529663689f * 1.4426950408889634f)

typedef float f4v __attribute__((ext_vector_type(4)));
typedef short b8v __attribute__((ext_vector_type(8)));
typedef uint  u2v __attribute__((ext_vector_type(2)));

__device__ __forceinline__ ushort f2b(float f){
  union { float f; uint32_t u; } x; x.f = f;
  return (ushort)((x.u + 0x7FFFu + ((x.u >> 16) & 1u)) >> 16);
}
__device__ __forceinline__ float b2f(ushort u){
  union { uint32_t u; float f; } x; x.u = ((uint32_t)u) << 16;
  return x.f;
}
__device__ __forceinline__ uint pk2b(float lo, float hi){
  return (((uint)f2b(hi)) << 16) | (uint)f2b(lo);
}
__device__ __forceinline__ float ex2(float x){ return __builtin_amdgcn_exp2f(x); }

// ---------------- weight transpose + cast: src [L][K][Nc] f32 -> dst [L][Nc][K] bf16
__global__ __launch_bounds__(256)
void wcast_kernel(const float* __restrict__ src, ushort* __restrict__ dst, int K, int Nc){
  __shared__ float t[32][33];
  int l = blockIdx.z;
  long base = (long)l * K * Nc;
  int n0 = blockIdx.x * 32, k0 = blockIdx.y * 32;
  int tx = threadIdx.x, ty = threadIdx.y; // (32,8)
  #pragma unroll
  for (int r = 0; r < 32; r += 8)
    t[ty + r][tx] = src[base + (long)(k0 + ty + r) * Nc + n0 + tx];
  __syncthreads();
  #pragma unroll
  for (int r = 0; r < 32; r += 8)
    dst[base + (long)(n0 + ty + r) * K + k0 + tx] = f2b(t[tx][ty + r]);
}

// ---------------- rel int32 -> uint8 (values < 37), once per call
__global__ __launch_bounds__(256)
void rel8_kernel(const int* __restrict__ rel, uint* __restrict__ rel8){
  long idx = (long)blockIdx.x * 256 + threadIdx.x;
  int4 v = ((const int4*)rel)[idx];
  rel8[idx] = (uint)(v.x & 255) | ((uint)(v.y & 255) << 8)
            | ((uint)(v.z & 255) << 16) | ((uint)(v.w & 255) << 24);
}

// ---------------- LayerNorm
template<int OUTB>
__global__ __launch_bounds__(64)
void ln_kernel(const float* __restrict__ x, const float* __restrict__ g, const float* __restrict__ b,
               ushort* __restrict__ ob, float* __restrict__ of){
  int row = blockIdx.x, lane = threadIdx.x;
  float4 v = ((const float4*)(x + (long)row * D_))[lane];
  float s = v.x + v.y + v.z + v.w;
  float s2 = v.x*v.x + v.y*v.y + v.z*v.z + v.w*v.w;
  #pragma unroll
  for (int o = 32; o; o >>= 1){ s += __shfl_xor(s, o); s2 += __shfl_xor(s2, o); }
  float mu = s * (1.f / D_);
  float var = (s2 - D_ * mu * mu) * (1.f / (D_ - 1));
  var = fmaxf(var, 0.f);
  float inv = 1.f / (sqrtf(var) + 1e-6f);
  float4 gv = ((const float4*)g)[lane];
  float4 bv = ((const float4*)b)[lane];
  float o0 = gv.x * (v.x - mu) * inv + bv.x;
  float o1 = gv.y * (v.y - mu) * inv + bv.y;
  float o2 = gv.z * (v.z - mu) * inv + bv.z;
  float o3 = gv.w * (v.w - mu) * inv + bv.w;
  if (OUTB){
    ushort4 u; u.x = f2b(o0); u.y = f2b(o1); u.z = f2b(o2); u.w = f2b(o3);
    ((ushort4*)ob)[(long)row * 64 + lane] = u;
  } else {
    float4 o; o.x = o0; o.y = o1; o.z = o2; o.w = o3;
    ((float4*)of)[(long)row * 64 + lane] = o;
  }
}

// ---------------- bf16 MFMA GEMM. QKV mode: head-split q/k to outB, V^T to outB2.
template<int QKV, int RELU, int RESID, int OUTF, int OUTB>
__global__ __launch_bounds__(256)
void gemm_kernel(const ushort* __restrict__ A,
                 const ushort* __restrict__ W0, const ushort* __restrict__ W1p, const ushort* __restrict__ W2p,
                 const float* __restrict__ B0, const float* __restrict__ B1p, const float* __restrict__ B2p,
                 float* __restrict__ resid, float* __restrict__ outF, ushort* __restrict__ outB,
                 ushort* __restrict__ outB2,
                 int M, int Nc, int K){
  __shared__ ushort Al[64 * 48];
  __shared__ ushort Bl[64 * 48];
  int tid = threadIdx.x;
  int lane = tid & 63, w = tid >> 6;
  int wm = w >> 1, wn = w & 1;
  int bn0 = blockIdx.x * 64, bm0 = blockIdx.y * 64;
  const ushort* WT; const float* bias; int wn0;
  if (QKV){
    int which = bn0 >> 8;
    WT = which == 0 ? W0 : (which == 1 ? W1p : W2p);
    bias = which == 0 ? B0 : (which == 1 ? B1p : B2p);
    wn0 = bn0 & 255;
  } else { WT = W0; bias = B0; wn0 = bn0; }

  int r4 = tid >> 2, c8 = (tid & 3) * 8;
  const ushort* ag = A + (long)(bm0 + r4) * K + c8;
  const ushort* bg = WT + (long)(wn0 + r4) * K + c8;

  f4v acc[2][2];
  #pragma unroll
  for (int i = 0; i < 2; ++i)
    #pragma unroll
    for (int j = 0; j < 2; ++j)
      acc[i][j] = (f4v){0.f, 0.f, 0.f, 0.f};

  int l16 = lane & 15, lg = lane >> 4;
  int arow0 = (wm * 32 + l16) * 48 + lg * 8;
  int brow0 = (wn * 32 + l16) * 48 + lg * 8;

  for (int k0 = 0; k0 < K; k0 += 32){
    b8v a8 = *(const b8v*)(ag + k0);
    b8v b8 = *(const b8v*)(bg + k0);
    __syncthreads();
    *(b8v*)&Al[r4 * 48 + c8] = a8;
    *(b8v*)&Bl[r4 * 48 + c8] = b8;
    __syncthreads();
    b8v a0 = *(const b8v*)&Al[arow0];
    b8v a1 = *(const b8v*)&Al[arow0 + 16 * 48];
    b8v b0 = *(const b8v*)&Bl[brow0];
    b8v b1 = *(const b8v*)&Bl[brow0 + 16 * 48];
    acc[0][0] = __builtin_amdgcn_mfma_f32_16x16x32_bf16(a0, b0, acc[0][0], 0, 0, 0);
    acc[0][1] = __builtin_amdgcn_mfma_f32_16x16x32_bf16(a0, b1, acc[0][1], 0, 0, 0);
    acc[1][0] = __builtin_amdgcn_mfma_f32_16x16x32_bf16(a1, b0, acc[1][0], 0, 0, 0);
    acc[1][1] = __builtin_amdgcn_mfma_f32_16x16x32_bf16(a1, b1, acc[1][1], 0, 0, 0);
  }
  #pragma unroll
  for (int fi = 0; fi < 2; ++fi)
    #pragma unroll
    for (int fj = 0; fj < 2; ++fj){
      int row0 = bm0 + wm * 32 + fi * 16 + lg * 4;
      int col = bn0 + wn * 32 + fj * 16 + l16;
      float vv[4];
      #pragma unroll
      for (int j = 0; j < 4; ++j) vv[j] = acc[fi][fj][j] + bias[QKV ? (col & 255) : col];
      if (QKV){
        int which = col >> 8, hh = (col >> 5) & 7, dk = col & 31;
        if (which == 2){
          ushort4 pk; pk.x = f2b(vv[0]); pk.y = f2b(vv[1]); pk.z = f2b(vv[2]); pk.w = f2b(vv[3]);
          *(ushort4*)(outB2 + (long)hh * 32768 + (long)dk * 1024 + row0) = pk;
        } else {
          #pragma unroll
          for (int j = 0; j < 4; ++j)
            outB[(long)which * 262144 + (long)hh * 32768 + (long)(row0 + j) * 32 + dk] = f2b(vv[j]);
        }
      } else {
        #pragma unroll
        for (int j = 0; j < 4; ++j){
          float v = vv[j];
          if (RELU) v = fmaxf(v, 0.f);
          long idx = (long)(row0 + j) * Nc + col;
          if (RESID) v += resid[idx];
          if (OUTF) outF[idx] = v;
          if (OUTB) outB[idx] = f2b(v);
        }
      }
    }
}

// ---------------- qr[h][i][r] (padded to 40) = SCL * q[h,i,:] . rel_k_emb[r]
__global__ __launch_bounds__(320)
void qr_kernel(const ushort* __restrict__ qb, const float* __restrict__ rke, float* __restrict__ qr){
  __shared__ float ql[256];
  int i = blockIdx.x, t = threadIdx.x;
  if (t < 256){
    int h = t >> 5, dk = t & 31;
    ql[t] = b2f(qb[(long)((h << 10) + i) * 32 + dk]);
  }
  __syncthreads();
  if (t < H_ * R_){
    int h = t / R_, r = t - h * R_;
    const float* qh = &ql[h * DK_];
    const float* e = rke + r * DK_;
    float acc = 0.f;
    #pragma unroll
    for (int d = 0; d < DK_; ++d) acc += qh[d] * e[d];
    qr[((long)(h << 10) + i) * 40 + r] = acc * SCL;
  }
}

// ---------------- barrier-free MFMA flash attention partial (j-split)
__global__ __launch_bounds__(256)
void attn_kernel(const ushort* __restrict__ qb, const ushort* __restrict__ kb,
                 const ushort* __restrict__ vbt, const float* __restrict__ qr,
                 const unsigned char* __restrict__ rel8, float* __restrict__ part){
  __shared__ float qr_l[64 * 40];
  __shared__ float prb[64 * 40];
  __shared__ uint  p_l[4 * 16 * 20];

  int tid = threadIdx.x, lane = tid & 63, w = tid >> 6;
  int l16 = lane & 15, g = lane >> 4;
  int ib0 = blockIdx.x * 64, h = blockIdx.y, js = blockIdx.z;
  int i_loc = w * 16 + l16;

  {
    const float* src = qr + (long)((h << 10) + ib0) * 40;
    for (int idx = tid; idx < 2560; idx += 256){ qr_l[idx] = src[idx]; prb[idx] = 0.f; }
  }
  __syncthreads();

  b8v qf = *(const b8v*)(qb + (long)((h << 10) + ib0 + i_loc) * 32 + g * 8);

  f4v oacc0 = (f4v){0.f,0.f,0.f,0.f}, oacc1 = (f4v){0.f,0.f,0.f,0.f};
  float m = -3.0e38f, lsum = 0.f;
  const float* qrr = &qr_l[i_loc * 40];
  float* prr = &prb[i_loc * 40];
  const unsigned char* relrow = rel8 + (long)(ib0 + i_loc) * N_ + js * (N_ / JS_);
  const ushort* kbh = kb + (long)(h << 10) * 32;
  const ushort* vth = vbt + (long)h * 32 * 1024;
  uint* pw = &p_l[w * 320 + l16 * 20];

  #pragma unroll
  for (int jt = 0; jt < N_ / JS_ / 32; ++jt){
    int j0 = js * (N_ / JS_) + jt * 32;
    b8v kf0 = *(const b8v*)(kbh + (long)(j0 + l16) * 32 + g * 8);
    b8v kf1 = *(const b8v*)(kbh + (long)(j0 + 16 + l16) * 32 + g * 8);
    b8v vt0 = *(const b8v*)(vth + (long)l16 * 1024 + j0 + g * 8);
    b8v vt1 = *(const b8v*)(vth + (long)(16 + l16) * 1024 + j0 + g * 8);
    uint rr0 = *(const uint*)(relrow + jt * 32 + g * 4);
    uint rr1 = *(const uint*)(relrow + jt * 32 + 16 + g * 4);

    f4v z = (f4v){0.f,0.f,0.f,0.f};
    f4v s0 = __builtin_amdgcn_mfma_f32_16x16x32_bf16(kf0, qf, z, 0, 0, 0);
    f4v s1 = __builtin_amdgcn_mfma_f32_16x16x32_bf16(kf1, qf, z, 0, 0, 0);

    int rix[8];
    float sv[8];
    #pragma unroll
    for (int e = 0; e < 4; ++e){
      rix[e]     = (rr0 >> (8 * e)) & 255;
      rix[e + 4] = (rr1 >> (8 * e)) & 255;
      sv[e]     = s0[e] * SCL + qrr[rix[e]];
      sv[e + 4] = s1[e] * SCL + qrr[rix[e + 4]];
    }
    float tmax = sv[0];
    #pragma unroll
    for (int e = 1; e < 8; ++e) tmax = fmaxf(tmax, sv[e]);
    tmax = fmaxf(tmax, __shfl_xor(tmax, 16));
    tmax = fmaxf(tmax, __shfl_xor(tmax, 32));

    // defer-max: rescale only when max grows by > 12 (exp2 domain)
    if (tmax - m > 12.f){
      float f = ex2(m - tmax);
      oacc0 *= f; oacc1 *= f; lsum *= f;
      #pragma unroll
      for (int b2 = 0; b2 < 10; ++b2){
        int bi = g * 10 + b2;
        if (bi < R_) prr[bi] *= f;
      }
      m = tmax;
    }
    float p[8], ps = 0.f;
    #pragma unroll
    for (int e = 0; e < 8; ++e){ p[e] = ex2(sv[e] - m); ps += p[e]; }
    ps += __shfl_xor(ps, 16);
    ps += __shfl_xor(ps, 32);
    lsum += ps;
    #pragma unroll
    for (int e = 0; e < 8; ++e) atomicAdd(&prr[rix[e]], p[e]);

    // repack P^T to bf16 B-fragment via wave-private LDS (no barrier)
    uint pk0 = pk2b(p[0], p[1]), pk1 = pk2b(p[2], p[3]);
    uint pk2 = pk2b(p[4], p[5]), pk3 = pk2b(p[6], p[7]);
    *(u2v*)&pw[g * 2]     = (u2v){pk0, pk1};
    *(u2v*)&pw[8 + g * 2] = (u2v){pk2, pk3};
    b8v pf = *(const b8v*)&pw[g * 4];
    oacc0 = __builtin_amdgcn_mfma_f32_16x16x32_bf16(vt0, pf, oacc0, 0, 0, 0);
    oacc1 = __builtin_amdgcn_mfma_f32_16x16x32_bf16(vt1, pf, oacc1, 0, 0, 0);
  }

  float* pp = part + ((long)(h * JS_ + js) * N_ + ib0 + i_loc) * 72;
  #pragma unroll
  for (int r2 = 0; r2 < 4; ++r2){
    pp[g * 4 + r2] = oacc0[r2];
    pp[16 + g * 4 + r2] = oacc1[r2];
  }
  #pragma unroll
  for (int b2 = 0; b2 < 10; ++b2){
    int bi = g * 10 + b2;
    if (bi < R_) pp[32 + bi] = prr[bi];
  }
  if (g == 0){ pp[69] = m; pp[70] = lsum; }
}

// ---------------- combine j-split partials, add pr@rel_v_emb, normalize, emit bf16
__global__ __launch_bounds__(256)
void combine_kernel(const float* __restrict__ part, const float* __restrict__ rve,
                    ushort* __restrict__ ob){
  __shared__ float prl[4][40];
  int tid = threadIdx.x, lane = tid & 63, w = tid >> 6;
  int i = blockIdx.x * 4 + w, h = blockIdx.y;
  int d = lane & 31;
  const float* pb = part + ((long)h * JS_) * N_ * 72 + (long)i * 72;
  float ms[JS_], ls[JS_], wf[JS_];
  float mstar = -3.0e38f;
  #pragma unroll
  for (int s = 0; s < JS_; ++s){
    ms[s] = pb[(long)s * N_ * 72 + 69];
    ls[s] = pb[(long)s * N_ * 72 + 70];
    mstar = fmaxf(mstar, ms[s]);
  }
  float lstar = 0.f;
  #pragma unroll
  for (int s = 0; s < JS_; ++s){ wf[s] = ex2(ms[s] - mstar); lstar += ls[s] * wf[s]; }
  float o1d = 0.f;
  #pragma unroll
  for (int s = 0; s < JS_; ++s) o1d += pb[(long)s * N_ * 72 + d] * wf[s];
  if (lane < R_){
    float prv = 0.f;
    #pragma unroll
    for (int s = 0; s < JS_; ++s) prv += pb[(long)s * N_ * 72 + 32 + lane] * wf[s];
    prl[w][lane] = prv;
  }
  float o2 = 0.f;
  for (int r = 0; r < R_; ++r) o2 += prl[w][r] * rve[r * DK_ + d];
  float val = (o1d + o2) / lstar;
  if (lane < 32) ob[(long)i * D_ + h * DK_ + d] = f2b(val);
}

extern "C" void kernel_launch(void* const* d_in, const int* in_sizes, int n_in,
                              void* d_out, int out_size, void* d_ws, size_t ws_size,
                              hipStream_t stream){
  const float* x    = (const float*)d_in[0];
  const int*   rel  = (const int*)d_in[1];
  const float* Wq   = (const float*)d_in[2];
  const float* bq   = (const float*)d_in[3];
  const float* Wk   = (const float*)d_in[4];
  const float* bk   = (const float*)d_in[5];
  const float* Wv   = (const float*)d_in[6];
  const float* bv   = (const float*)d_in[7];
  const float* Wo   = (const float*)d_in[8];
  const float* bo   = (const float*)d_in[9];
  const float* rke  = (const float*)d_in[10];
  const float* rve  = (const float*)d_in[11];
  const float* W1   = (const float*)d_in[12];
  const float* b1   = (const float*)d_in[13];
  const float* W2   = (const float*)d_in[14];
  const float* b2   = (const float*)d_in[15];
  const float* ln1g = (const float*)d_in[16];
  const float* ln1b = (const float*)d_in[17];
  const float* ln2g = (const float*)d_in[18];
  const float* ln2b = (const float*)d_in[19];
  const float* lnfg = (const float*)d_in[20];
  const float* lnfb = (const float*)d_in[21];

  char* wsb = (char*)d_ws;
  size_t off = 0;
  auto alloc = [&](size_t bytes){ void* p = wsb + off; off += (bytes + 255) & ~255ull; return p; };
  float*  xw   = (float*) alloc((size_t)N_ * D_ * 4);
  ushort* qkvb = (ushort*)alloc((size_t)3 * H_ * N_ * DK_ * 2);
  ushort* vbt  = (ushort*)alloc((size_t)H_ * DK_ * N_ * 2);
  float*  qr   = (float*) alloc((size_t)H_ * N_ * 40 * 4);
  ushort* xnb  = (ushort*)alloc((size_t)N_ * D_ * 2);
  ushort* obf  = (ushort*)alloc((size_t)N_ * D_ * 2);
  float*  part = (float*) alloc((size_t)H_ * JS_ * N_ * 72 * 4);
  ushort* hidb = (ushort*)part;  // alias: part dead during FFN
  uint*   rel8 = (uint*)  alloc((size_t)N_ * N_);
  ushort* wqT  = (ushort*)alloc((size_t)L_ * D_ * D_ * 2);
  ushort* wkT  = (ushort*)alloc((size_t)L_ * D_ * D_ * 2);
  ushort* wvT  = (ushort*)alloc((size_t)L_ * D_ * D_ * 2);
  ushort* woT  = (ushort*)alloc((size_t)L_ * D_ * D_ * 2);
  ushort* w1T  = (ushort*)alloc((size_t)L_ * D_ * FF_ * 2);
  ushort* w2T  = (ushort*)alloc((size_t)L_ * D_ * FF_ * 2);
  (void)ws_size; (void)in_sizes; (void)n_in; (void)out_size;

  ushort* qb = qkvb;
  ushort* kb = qkvb + (size_t)H_ * N_ * DK_;

  dim3 tb(32, 8);
  wcast_kernel<<<dim3(D_/32,  D_/32,  L_), tb, 0, stream>>>(Wq, wqT, D_, D_);
  wcast_kernel<<<dim3(D_/32,  D_/32,  L_), tb, 0, stream>>>(Wk, wkT, D_, D_);
  wcast_kernel<<<dim3(D_/32,  D_/32,  L_), tb, 0, stream>>>(Wv, wvT, D_, D_);
  wcast_kernel<<<dim3(D_/32,  D_/32,  L_), tb, 0, stream>>>(Wo, woT, D_, D_);
  wcast_kernel<<<dim3(FF_/32, D_/32,  L_), tb, 0, stream>>>(W1, w1T, D_, FF_);
  wcast_kernel<<<dim3(D_/32,  FF_/32, L_), tb, 0, stream>>>(W2, w2T, FF_, D_);
  rel8_kernel<<<N_ * N_ / 1024, 256, 0, stream>>>(rel, rel8);

  hipMemcpyAsync(xw, x, (size_t)N_ * D_ * 4, hipMemcpyDeviceToDevice, stream);

  for (int l = 0; l < L_; ++l){
    ln_kernel<1><<<N_, 64, 0, stream>>>(xw, ln1g + l * D_, ln1b + l * D_, xnb, nullptr);
    gemm_kernel<1,0,0,0,1><<<dim3(768/64, N_/64), 256, 0, stream>>>(
        xnb, wqT + (size_t)l * D_ * D_, wkT + (size_t)l * D_ * D_, wvT + (size_t)l * D_ * D_,
        bq + l * D_, bk + l * D_, bv + l * D_,
        nullptr, nullptr, qkvb, vbt, N_, 768, D_);
    qr_kernel<<<N_, 320, 0, stream>>>(qb, rke + (size_t)l * R_ * DK_, qr);
    attn_kernel<<<dim3(N_/64, H_, JS_), 256, 0, stream>>>(qb, kb, vbt, qr, (const unsigned char*)rel8, part);
    combine_kernel<<<dim3(N_/4, H_), 256, 0, stream>>>(part, rve + (size_t)l * R_ * DK_, obf);
    gemm_kernel<0,0,1,1,0><<<dim3(D_/64, N_/64), 256, 0, stream>>>(
        obf, woT + (size_t)l * D_ * D_, nullptr, nullptr,
        bo + l * D_, nullptr, nullptr,
        xw, xw, nullptr, nullptr, N_, D_, D_);
    ln_kernel<1><<<N_, 64, 0, stream>>>(xw, ln2g + l * D_, ln2b + l * D_, xnb, nullptr);
    gemm_kernel<0,1,0,0,1><<<dim3(FF_/64, N_/64), 256, 0, stream>>>(
        xnb, w1T + (size_t)l * D_ * FF_, nullptr, nullptr,
        b1 + l * FF_, nullptr, nullptr,
        nullptr, nullptr, hidb, nullptr, N_, FF_, D_);
    gemm_kernel<0,0,1,1,0><<<dim3(D_/64, N_/64), 256, 0, stream>>>(
        hidb, w2T + (size_t)l * FF_ * D_, nullptr, nullptr,
        b2 + l * D_, nullptr, nullptr,
        xw, xw, nullptr, nullptr, N_, D_, FF_);
  }
  ln_kernel<0><<<N_, 64, 0, stream>>>(xw, lnfg, lnfb, nullptr, (float*)d_out);
}

// Round 4
// 787.831 us; speedup vs baseline: 1.8039x; 1.1067x over previous
//
#include <hip/hip_runtime.h>
#include <stdint.h>

#define L_ 8
#define D_ 256
#define H_ 8
#define DK_ 32
#define FF_ 1024
#define R_ 37
#define N_ 1024
#define AIB 32   // i-rows per attention block

// scale * log2(e): attention runs in exp2 domain
#define SCL (0.17677669529663689f * 1.4426950408889634f)

typedef float f4v __attribute__((ext_vector_type(4)));
typedef short b8v __attribute__((ext_vector_type(8)));
typedef uint  u2v __attribute__((ext_vector_type(2)));

__device__ __forceinline__ ushort f2b(float f){
  union { float f; uint32_t u; } x; x.f = f;
  return (ushort)((x.u + 0x7FFFu + ((x.u >> 16) & 1u)) >> 16);
}
__device__ __forceinline__ float b2f(ushort u){
  union { uint32_t u; float f; } x; x.u = ((uint32_t)u) << 16;
  return x.f;
}
__device__ __forceinline__ uint pk2b(float lo, float hi){
  return (((uint)f2b(hi)) << 16) | (uint)f2b(lo);
}
__device__ __forceinline__ float ex2(float x){ return __builtin_amdgcn_exp2f(x); }

// ---------------- weight transpose + cast: src [L][K][Nc] f32 -> dst [L][Nc][K] bf16
__global__ __launch_bounds__(256)
void wcast_kernel(const float* __restrict__ src, ushort* __restrict__ dst, int K, int Nc){
  __shared__ float t[32][33];
  int l = blockIdx.z;
  long base = (long)l * K * Nc;
  int n0 = blockIdx.x * 32, k0 = blockIdx.y * 32;
  int tx = threadIdx.x, ty = threadIdx.y; // (32,8)
  #pragma unroll
  for (int r = 0; r < 32; r += 8)
    t[ty + r][tx] = src[base + (long)(k0 + ty + r) * Nc + n0 + tx];
  __syncthreads();
  #pragma unroll
  for (int r = 0; r < 32; r += 8)
    dst[base + (long)(n0 + ty + r) * K + k0 + tx] = f2b(t[tx][ty + r]);
}

// ---------------- rel int32 -> uint8 (values < 37), once per call
__global__ __launch_bounds__(256)
void rel8_kernel(const int* __restrict__ rel, uint* __restrict__ rel8){
  long idx = (long)blockIdx.x * 256 + threadIdx.x;
  int4 v = ((const int4*)rel)[idx];
  rel8[idx] = (uint)(v.x & 255) | ((uint)(v.y & 255) << 8)
            | ((uint)(v.z & 255) << 16) | ((uint)(v.w & 255) << 24);
}

// ---------------- LayerNorm
template<int OUTB>
__global__ __launch_bounds__(64)
void ln_kernel(const float* __restrict__ x, const float* __restrict__ g, const float* __restrict__ b,
               ushort* __restrict__ ob, float* __restrict__ of){
  int row = blockIdx.x, lane = threadIdx.x;
  float4 v = ((const float4*)(x + (long)row * D_))[lane];
  float s = v.x + v.y + v.z + v.w;
  float s2 = v.x*v.x + v.y*v.y + v.z*v.z + v.w*v.w;
  #pragma unroll
  for (int o = 32; o; o >>= 1){ s += __shfl_xor(s, o); s2 += __shfl_xor(s2, o); }
  float mu = s * (1.f / D_);
  float var = (s2 - D_ * mu * mu) * (1.f / (D_ - 1));
  var = fmaxf(var, 0.f);
  float inv = 1.f / (sqrtf(var) + 1e-6f);
  float4 gv = ((const float4*)g)[lane];
  float4 bv = ((const float4*)b)[lane];
  float o0 = gv.x * (v.x - mu) * inv + bv.x;
  float o1 = gv.y * (v.y - mu) * inv + bv.y;
  float o2 = gv.z * (v.z - mu) * inv + bv.z;
  float o3 = gv.w * (v.w - mu) * inv + bv.w;
  if (OUTB){
    ushort4 u; u.x = f2b(o0); u.y = f2b(o1); u.z = f2b(o2); u.w = f2b(o3);
    ((ushort4*)ob)[(long)row * 64 + lane] = u;
  } else {
    float4 o; o.x = o0; o.y = o1; o.z = o2; o.w = o3;
    ((float4*)of)[(long)row * 64 + lane] = o;
  }
}

// ---------------- bf16 MFMA GEMM. QKV mode: head-split q/k to outB, V^T to outB2.
template<int QKV, int RELU, int RESID, int OUTF, int OUTB>
__global__ __launch_bounds__(256)
void gemm_kernel(const ushort* __restrict__ A,
                 const ushort* __restrict__ W0, const ushort* __restrict__ W1p, const ushort* __restrict__ W2p,
                 const float* __restrict__ B0, const float* __restrict__ B1p, const float* __restrict__ B2p,
                 float* __restrict__ resid, float* __restrict__ outF, ushort* __restrict__ outB,
                 ushort* __restrict__ outB2,
                 int M, int Nc, int K){
  __shared__ ushort Al[64 * 48];
  __shared__ ushort Bl[64 * 48];
  int tid = threadIdx.x;
  int lane = tid & 63, w = tid >> 6;
  int wm = w >> 1, wn = w & 1;
  int bn0 = blockIdx.x * 64, bm0 = blockIdx.y * 64;
  const ushort* WT; const float* bias; int wn0;
  if (QKV){
    int which = bn0 >> 8;
    WT = which == 0 ? W0 : (which == 1 ? W1p : W2p);
    bias = which == 0 ? B0 : (which == 1 ? B1p : B2p);
    wn0 = bn0 & 255;
  } else { WT = W0; bias = B0; wn0 = bn0; }

  int r4 = tid >> 2, c8 = (tid & 3) * 8;
  const ushort* ag = A + (long)(bm0 + r4) * K + c8;
  const ushort* bg = WT + (long)(wn0 + r4) * K + c8;

  f4v acc[2][2];
  #pragma unroll
  for (int i = 0; i < 2; ++i)
    #pragma unroll
    for (int j = 0; j < 2; ++j)
      acc[i][j] = (f4v){0.f, 0.f, 0.f, 0.f};

  int l16 = lane & 15, lg = lane >> 4;
  int arow0 = (wm * 32 + l16) * 48 + lg * 8;
  int brow0 = (wn * 32 + l16) * 48 + lg * 8;

  for (int k0 = 0; k0 < K; k0 += 32){
    b8v a8 = *(const b8v*)(ag + k0);
    b8v b8 = *(const b8v*)(bg + k0);
    __syncthreads();
    *(b8v*)&Al[r4 * 48 + c8] = a8;
    *(b8v*)&Bl[r4 * 48 + c8] = b8;
    __syncthreads();
    b8v a0 = *(const b8v*)&Al[arow0];
    b8v a1 = *(const b8v*)&Al[arow0 + 16 * 48];
    b8v b0 = *(const b8v*)&Bl[brow0];
    b8v b1 = *(const b8v*)&Bl[brow0 + 16 * 48];
    acc[0][0] = __builtin_amdgcn_mfma_f32_16x16x32_bf16(a0, b0, acc[0][0], 0, 0, 0);
    acc[0][1] = __builtin_amdgcn_mfma_f32_16x16x32_bf16(a0, b1, acc[0][1], 0, 0, 0);
    acc[1][0] = __builtin_amdgcn_mfma_f32_16x16x32_bf16(a1, b0, acc[1][0], 0, 0, 0);
    acc[1][1] = __builtin_amdgcn_mfma_f32_16x16x32_bf16(a1, b1, acc[1][1], 0, 0, 0);
  }
  #pragma unroll
  for (int fi = 0; fi < 2; ++fi)
    #pragma unroll
    for (int fj = 0; fj < 2; ++fj){
      int row0 = bm0 + wm * 32 + fi * 16 + lg * 4;
      int col = bn0 + wn * 32 + fj * 16 + l16;
      float vv[4];
      #pragma unroll
      for (int j = 0; j < 4; ++j) vv[j] = acc[fi][fj][j] + bias[QKV ? (col & 255) : col];
      if (QKV){
        int which = col >> 8, hh = (col >> 5) & 7, dk = col & 31;
        if (which == 2){
          ushort4 pk; pk.x = f2b(vv[0]); pk.y = f2b(vv[1]); pk.z = f2b(vv[2]); pk.w = f2b(vv[3]);
          *(ushort4*)(outB2 + (long)hh * 32768 + (long)dk * 1024 + row0) = pk;
        } else {
          #pragma unroll
          for (int j = 0; j < 4; ++j)
            outB[(long)which * 262144 + (long)hh * 32768 + (long)(row0 + j) * 32 + dk] = f2b(vv[j]);
        }
      } else {
        #pragma unroll
        for (int j = 0; j < 4; ++j){
          float v = vv[j];
          if (RELU) v = fmaxf(v, 0.f);
          long idx = (long)(row0 + j) * Nc + col;
          if (RESID) v += resid[idx];
          if (OUTF) outF[idx] = v;
          if (OUTB) outB[idx] = f2b(v);
        }
      }
    }
}

// ---------------- fully-fused MFMA flash attention (qr + flash + bins + combine)
// grid (N/32, H), 512 threads = 8 waves: 4-way j-split x 2-way i-split
__global__ __launch_bounds__(512)
void attn_kernel(const ushort* __restrict__ qb, const ushort* __restrict__ kb,
                 const ushort* __restrict__ vbt, const float* __restrict__ rke,
                 const float* __restrict__ rve,
                 const unsigned char* __restrict__ rel8, ushort* __restrict__ ob){
  __shared__ float q_l[AIB * 32];         // f32 q rows (for qr dots)
  __shared__ float qr_l[AIB * 40];        // qr bias per row
  __shared__ float prb[4 * AIB * 40];     // relation bins per (js,row)
  __shared__ uint  p_l[8 * 16 * 20];      // P^T repack, wave-private
  __shared__ float part_l[4 * AIB * 34];  // per (js,row): o[32], m, l
  __shared__ float wf_l[4 * AIB];
  __shared__ float lrow_l[AIB];

  int tid = threadIdx.x, lane = tid & 63, w = tid >> 6;
  int l16 = lane & 15, g = lane >> 4;
  int ib0 = blockIdx.x * AIB, h = blockIdx.y;
  int js = w >> 1, ig = w & 1;
  int ir = ig * 16 + l16;

  // stage q (f32) + zero bins
  if (tid < 256){
    int row = tid >> 3, d4 = (tid & 7) * 4;
    ushort4 u = *(const ushort4*)(qb + (long)((h << 10) + ib0 + row) * 32 + d4);
    q_l[row * 32 + d4 + 0] = b2f(u.x);
    q_l[row * 32 + d4 + 1] = b2f(u.y);
    q_l[row * 32 + d4 + 2] = b2f(u.z);
    q_l[row * 32 + d4 + 3] = b2f(u.w);
  }
  for (int idx = tid; idx < 4 * AIB * 40; idx += 512) prb[idx] = 0.f;
  __syncthreads();

  // qr[row][r] = SCL * q[row,:] . rke[r,:]
  for (int slot = tid; slot < AIB * 40; slot += 512){
    int row = slot / 40, r = slot - row * 40;
    if (r < R_){
      const float* qh = &q_l[row * 32];
      const float* e = rke + r * 32;
      float acc = 0.f;
      #pragma unroll
      for (int d = 0; d < 32; ++d) acc += qh[d] * e[d];
      qr_l[slot] = acc * SCL;
    }
  }
  __syncthreads();

  b8v qf = *(const b8v*)(qb + (long)((h << 10) + ib0 + ir) * 32 + g * 8);

  f4v oacc0 = (f4v){0.f,0.f,0.f,0.f}, oacc1 = (f4v){0.f,0.f,0.f,0.f};
  float m = -3.0e38f, lsum = 0.f;
  const float* qrr = &qr_l[ir * 40];
  float* prr = &prb[(js * AIB + ir) * 40];
  const unsigned char* relrow = rel8 + (long)(ib0 + ir) * N_ + js * 256;
  const ushort* kbh = kb + (long)(h << 10) * 32;
  const ushort* vth = vbt + (long)h * 32 * 1024;
  uint* pw = &p_l[w * 320 + l16 * 20];

  #pragma unroll
  for (int jt = 0; jt < 8; ++jt){
    int j0 = js * 256 + jt * 32;
    b8v kf0 = *(const b8v*)(kbh + (long)(j0 + l16) * 32 + g * 8);
    b8v kf1 = *(const b8v*)(kbh + (long)(j0 + 16 + l16) * 32 + g * 8);
    b8v vt0 = *(const b8v*)(vth + (long)l16 * 1024 + j0 + g * 8);
    b8v vt1 = *(const b8v*)(vth + (long)(16 + l16) * 1024 + j0 + g * 8);
    uint rr0 = *(const uint*)(relrow + jt * 32 + g * 4);
    uint rr1 = *(const uint*)(relrow + jt * 32 + 16 + g * 4);

    f4v z = (f4v){0.f,0.f,0.f,0.f};
    f4v s0 = __builtin_amdgcn_mfma_f32_16x16x32_bf16(kf0, qf, z, 0, 0, 0);
    f4v s1 = __builtin_amdgcn_mfma_f32_16x16x32_bf16(kf1, qf, z, 0, 0, 0);

    int rix[8];
    float sv[8];
    #pragma unroll
    for (int e = 0; e < 4; ++e){
      rix[e]     = (rr0 >> (8 * e)) & 255;
      rix[e + 4] = (rr1 >> (8 * e)) & 255;
      sv[e]     = s0[e] * SCL + qrr[rix[e]];
      sv[e + 4] = s1[e] * SCL + qrr[rix[e + 4]];
    }
    float tmax = sv[0];
    #pragma unroll
    for (int e = 1; e < 8; ++e) tmax = fmaxf(tmax, sv[e]);
    tmax = fmaxf(tmax, __shfl_xor(tmax, 16));
    tmax = fmaxf(tmax, __shfl_xor(tmax, 32));

    // defer-max: rescale only when max grows by > 12 (exp2 domain)
    if (tmax - m > 12.f){
      float f = ex2(m - tmax);
      oacc0 *= f; oacc1 *= f; lsum *= f;
      #pragma unroll
      for (int b2 = 0; b2 < 10; ++b2){
        int bi = g * 10 + b2;
        if (bi < R_) prr[bi] *= f;
      }
      m = tmax;
    }
    float p[8], ps = 0.f;
    #pragma unroll
    for (int e = 0; e < 8; ++e){ p[e] = ex2(sv[e] - m); ps += p[e]; }
    ps += __shfl_xor(ps, 16);
    ps += __shfl_xor(ps, 32);
    lsum += ps;
    #pragma unroll
    for (int e = 0; e < 8; ++e) atomicAdd(&prr[rix[e]], p[e]);

    // repack P^T to bf16 B-fragment via wave-private LDS (no barrier)
    uint pk0 = pk2b(p[0], p[1]), pk1 = pk2b(p[2], p[3]);
    uint pk2 = pk2b(p[4], p[5]), pk3 = pk2b(p[6], p[7]);
    *(u2v*)&pw[g * 2]     = (u2v){pk0, pk1};
    *(u2v*)&pw[8 + g * 2] = (u2v){pk2, pk3};
    b8v pf = *(const b8v*)&pw[g * 4];
    oacc0 = __builtin_amdgcn_mfma_f32_16x16x32_bf16(vt0, pf, oacc0, 0, 0, 0);
    oacc1 = __builtin_amdgcn_mfma_f32_16x16x32_bf16(vt1, pf, oacc1, 0, 0, 0);
  }

  // write per-wave partial into LDS
  {
    float* pp = &part_l[(js * AIB + ir) * 34];
    #pragma unroll
    for (int e = 0; e < 4; ++e){
      pp[g * 4 + e] = oacc0[e];
      pp[16 + g * 4 + e] = oacc1[e];
    }
    if (g == 0){ pp[32] = m; pp[33] = lsum; }
  }
  __syncthreads();

  // per-row combine weights
  if (tid < AIB){
    int row = tid;
    float ms[4], ls[4];
    float mstar = -3.0e38f;
    #pragma unroll
    for (int s = 0; s < 4; ++s){
      ms[s] = part_l[(s * AIB + row) * 34 + 32];
      ls[s] = part_l[(s * AIB + row) * 34 + 33];
      mstar = fmaxf(mstar, ms[s]);
    }
    float lstar = 0.f;
    #pragma unroll
    for (int s = 0; s < 4; ++s){
      float wfv = ex2(ms[s] - mstar);
      wf_l[s * AIB + row] = wfv;
      lstar += ls[s] * wfv;
    }
    lrow_l[row] = lstar;
  }
  __syncthreads();

  // merge bins across j-splits (into s=0 region)
  for (int slot = tid; slot < AIB * 40; slot += 512){
    int row = slot / 40;
    float acc = 0.f;
    #pragma unroll
    for (int s = 0; s < 4; ++s) acc += prb[(s * AIB) * 40 + slot] * wf_l[s * AIB + row];
    prb[slot] = acc;
  }
  __syncthreads();

  // final output: o = (sum_s wf*o_s + bins @ rve) / lstar
  for (int slot = tid; slot < AIB * 32; slot += 512){
    int row = slot >> 5, d = slot & 31;
    float o1 = 0.f;
    #pragma unroll
    for (int s = 0; s < 4; ++s) o1 += part_l[(s * AIB + row) * 34 + d] * wf_l[s * AIB + row];
    float o2 = 0.f;
    #pragma unroll
    for (int r = 0; r < R_; ++r) o2 += prb[row * 40 + r] * rve[r * 32 + d];
    float val = (o1 + o2) / lrow_l[row];
    ob[(long)(ib0 + row) * D_ + h * 32 + d] = f2b(val);
  }
}

extern "C" void kernel_launch(void* const* d_in, const int* in_sizes, int n_in,
                              void* d_out, int out_size, void* d_ws, size_t ws_size,
                              hipStream_t stream){
  const float* x    = (const float*)d_in[0];
  const int*   rel  = (const int*)d_in[1];
  const float* Wq   = (const float*)d_in[2];
  const float* bq   = (const float*)d_in[3];
  const float* Wk   = (const float*)d_in[4];
  const float* bk   = (const float*)d_in[5];
  const float* Wv   = (const float*)d_in[6];
  const float* bv   = (const float*)d_in[7];
  const float* Wo   = (const float*)d_in[8];
  const float* bo   = (const float*)d_in[9];
  const float* rke  = (const float*)d_in[10];
  const float* rve  = (const float*)d_in[11];
  const float* W1   = (const float*)d_in[12];
  const float* b1   = (const float*)d_in[13];
  const float* W2   = (const float*)d_in[14];
  const float* b2   = (const float*)d_in[15];
  const float* ln1g = (const float*)d_in[16];
  const float* ln1b = (const float*)d_in[17];
  const float* ln2g = (const float*)d_in[18];
  const float* ln2b = (const float*)d_in[19];
  const float* lnfg = (const float*)d_in[20];
  const float* lnfb = (const float*)d_in[21];

  char* wsb = (char*)d_ws;
  size_t off = 0;
  auto alloc = [&](size_t bytes){ void* p = wsb + off; off += (bytes + 255) & ~255ull; return p; };
  float*  xw   = (float*) alloc((size_t)N_ * D_ * 4);
  ushort* qkvb = (ushort*)alloc((size_t)3 * H_ * N_ * DK_ * 2);
  ushort* vbt  = (ushort*)alloc((size_t)H_ * DK_ * N_ * 2);
  ushort* xnb  = (ushort*)alloc((size_t)N_ * D_ * 2);
  ushort* obf  = (ushort*)alloc((size_t)N_ * D_ * 2);
  ushort* hidb = (ushort*)alloc((size_t)N_ * FF_ * 2);
  uint*   rel8 = (uint*)  alloc((size_t)N_ * N_);
  ushort* wqT  = (ushort*)alloc((size_t)L_ * D_ * D_ * 2);
  ushort* wkT  = (ushort*)alloc((size_t)L_ * D_ * D_ * 2);
  ushort* wvT  = (ushort*)alloc((size_t)L_ * D_ * D_ * 2);
  ushort* woT  = (ushort*)alloc((size_t)L_ * D_ * D_ * 2);
  ushort* w1T  = (ushort*)alloc((size_t)L_ * D_ * FF_ * 2);
  ushort* w2T  = (ushort*)alloc((size_t)L_ * D_ * FF_ * 2);
  (void)ws_size; (void)in_sizes; (void)n_in; (void)out_size;

  ushort* qb = qkvb;
  ushort* kb = qkvb + (size_t)H_ * N_ * DK_;

  dim3 tb(32, 8);
  wcast_kernel<<<dim3(D_/32,  D_/32,  L_), tb, 0, stream>>>(Wq, wqT, D_, D_);
  wcast_kernel<<<dim3(D_/32,  D_/32,  L_), tb, 0, stream>>>(Wk, wkT, D_, D_);
  wcast_kernel<<<dim3(D_/32,  D_/32,  L_), tb, 0, stream>>>(Wv, wvT, D_, D_);
  wcast_kernel<<<dim3(D_/32,  D_/32,  L_), tb, 0, stream>>>(Wo, woT, D_, D_);
  wcast_kernel<<<dim3(FF_/32, D_/32,  L_), tb, 0, stream>>>(W1, w1T, D_, FF_);
  wcast_kernel<<<dim3(D_/32,  FF_/32, L_), tb, 0, stream>>>(W2, w2T, FF_, D_);
  rel8_kernel<<<N_ * N_ / 1024, 256, 0, stream>>>(rel, rel8);

  hipMemcpyAsync(xw, x, (size_t)N_ * D_ * 4, hipMemcpyDeviceToDevice, stream);

  for (int l = 0; l < L_; ++l){
    ln_kernel<1><<<N_, 64, 0, stream>>>(xw, ln1g + l * D_, ln1b + l * D_, xnb, nullptr);
    gemm_kernel<1,0,0,0,1><<<dim3(768/64, N_/64), 256, 0, stream>>>(
        xnb, wqT + (size_t)l * D_ * D_, wkT + (size_t)l * D_ * D_, wvT + (size_t)l * D_ * D_,
        bq + l * D_, bk + l * D_, bv + l * D_,
        nullptr, nullptr, qkvb, vbt, N_, 768, D_);
    attn_kernel<<<dim3(N_/AIB, H_), 512, 0, stream>>>(
        qb, kb, vbt, rke + (size_t)l * R_ * DK_, rve + (size_t)l * R_ * DK_,
        (const unsigned char*)rel8, obf);
    gemm_kernel<0,0,1,1,0><<<dim3(D_/64, N_/64), 256, 0, stream>>>(
        obf, woT + (size_t)l * D_ * D_, nullptr, nullptr,
        bo + l * D_, nullptr, nullptr,
        xw, xw, nullptr, nullptr, N_, D_, D_);
    ln_kernel<1><<<N_, 64, 0, stream>>>(xw, ln2g + l * D_, ln2b + l * D_, xnb, nullptr);
    gemm_kernel<0,1,0,0,1><<<dim3(FF_/64, N_/64), 256, 0, stream>>>(
        xnb, w1T + (size_t)l * D_ * FF_, nullptr, nullptr,
        b1 + l * FF_, nullptr, nullptr,
        nullptr, nullptr, hidb, nullptr, N_, FF_, D_);
    gemm_kernel<0,0,1,1,0><<<dim3(D_/64, N_/64), 256, 0, stream>>>(
        hidb, w2T + (size_t)l * FF_ * D_, nullptr, nullptr,
        b2 + l * D_, nullptr, nullptr,
        xw, xw, nullptr, nullptr, N_, D_, FF_);
  }
  ln_kernel<0><<<N_, 64, 0, stream>>>(xw, lnfg, lnfb, nullptr, (float*)d_out);
}

// Round 5
// 784.872 us; speedup vs baseline: 1.8107x; 1.0038x over previous
//
#include <hip/hip_runtime.h>
#include <stdint.h>

#define L_ 8
#define D_ 256
#define H_ 8
#define DK_ 32
#define FF_ 1024
#define R_ 37
#define N_ 1024
#define AIB 32   // i-rows per attention block

// scale * log2(e): attention runs in exp2 domain
#define SCL (0.17677669529663689f * 1.4426950408889634f)

typedef float f4v __attribute__((ext_vector_type(4)));
typedef short b8v __attribute__((ext_vector_type(8)));
typedef uint  u2v __attribute__((ext_vector_type(2)));

__device__ __forceinline__ ushort f2b(float f){
  union { float f; uint32_t u; } x; x.f = f;
  return (ushort)((x.u + 0x7FFFu + ((x.u >> 16) & 1u)) >> 16);
}
__device__ __forceinline__ float b2f(ushort u){
  union { uint32_t u; float f; } x; x.u = ((uint32_t)u) << 16;
  return x.f;
}
__device__ __forceinline__ uint pk2b(float lo, float hi){
  return (((uint)f2b(hi)) << 16) | (uint)f2b(lo);
}
__device__ __forceinline__ float ex2(float x){ return __builtin_amdgcn_exp2f(x); }

// native LDS float add (avoids the CAS loop HIP emits for atomicAdd(float*) on LDS
// without -munsafe-fp-atomics). On gfx9+ the low 32 bits of a flat LDS pointer
// are the DS byte offset.
__device__ __forceinline__ void lds_fadd(float* p, float v){
  asm volatile("ds_add_f32 %0, %1" :: "v"((uint)(uintptr_t)p), "v"(v) : "memory");
}

// ---------------- weight transpose + cast: src [L][K][Nc] f32 -> dst [L][Nc][K] bf16
__global__ __launch_bounds__(256)
void wcast_kernel(const float* __restrict__ src, ushort* __restrict__ dst, int K, int Nc){
  __shared__ float t[32][33];
  int l = blockIdx.z;
  long base = (long)l * K * Nc;
  int n0 = blockIdx.x * 32, k0 = blockIdx.y * 32;
  int tx = threadIdx.x, ty = threadIdx.y; // (32,8)
  #pragma unroll
  for (int r = 0; r < 32; r += 8)
    t[ty + r][tx] = src[base + (long)(k0 + ty + r) * Nc + n0 + tx];
  __syncthreads();
  #pragma unroll
  for (int r = 0; r < 32; r += 8)
    dst[base + (long)(n0 + ty + r) * K + k0 + tx] = f2b(t[tx][ty + r]);
}

// ---------------- rel int32 -> uint8 (values < 37), once per call
__global__ __launch_bounds__(256)
void rel8_kernel(const int* __restrict__ rel, uint* __restrict__ rel8){
  long idx = (long)blockIdx.x * 256 + threadIdx.x;
  int4 v = ((const int4*)rel)[idx];
  rel8[idx] = (uint)(v.x & 255) | ((uint)(v.y & 255) << 8)
            | ((uint)(v.z & 255) << 16) | ((uint)(v.w & 255) << 24);
}

// ---------------- LayerNorm
template<int OUTB>
__global__ __launch_bounds__(64)
void ln_kernel(const float* __restrict__ x, const float* __restrict__ g, const float* __restrict__ b,
               ushort* __restrict__ ob, float* __restrict__ of){
  int row = blockIdx.x, lane = threadIdx.x;
  float4 v = ((const float4*)(x + (long)row * D_))[lane];
  float s = v.x + v.y + v.z + v.w;
  float s2 = v.x*v.x + v.y*v.y + v.z*v.z + v.w*v.w;
  #pragma unroll
  for (int o = 32; o; o >>= 1){ s += __shfl_xor(s, o); s2 += __shfl_xor(s2, o); }
  float mu = s * (1.f / D_);
  float var = (s2 - D_ * mu * mu) * (1.f / (D_ - 1));
  var = fmaxf(var, 0.f);
  float inv = 1.f / (sqrtf(var) + 1e-6f);
  float4 gv = ((const float4*)g)[lane];
  float4 bv = ((const float4*)b)[lane];
  float o0 = gv.x * (v.x - mu) * inv + bv.x;
  float o1 = gv.y * (v.y - mu) * inv + bv.y;
  float o2 = gv.z * (v.z - mu) * inv + bv.z;
  float o3 = gv.w * (v.w - mu) * inv + bv.w;
  if (OUTB){
    ushort4 u; u.x = f2b(o0); u.y = f2b(o1); u.z = f2b(o2); u.w = f2b(o3);
    ((ushort4*)ob)[(long)row * 64 + lane] = u;
  } else {
    float4 o; o.x = o0; o.y = o1; o.z = o2; o.w = o3;
    ((float4*)of)[(long)row * 64 + lane] = o;
  }
}

// ---------------- bf16 MFMA GEMM. QKV mode: head-split q/k to outB, V^T to outB2.
template<int QKV, int RELU, int RESID, int OUTF, int OUTB>
__global__ __launch_bounds__(256)
void gemm_kernel(const ushort* __restrict__ A,
                 const ushort* __restrict__ W0, const ushort* __restrict__ W1p, const ushort* __restrict__ W2p,
                 const float* __restrict__ B0, const float* __restrict__ B1p, const float* __restrict__ B2p,
                 float* __restrict__ resid, float* __restrict__ outF, ushort* __restrict__ outB,
                 ushort* __restrict__ outB2,
                 int M, int Nc, int K){
  __shared__ ushort Al[64 * 48];
  __shared__ ushort Bl[64 * 48];
  int tid = threadIdx.x;
  int lane = tid & 63, w = tid >> 6;
  int wm = w >> 1, wn = w & 1;
  int bn0 = blockIdx.x * 64, bm0 = blockIdx.y * 64;
  const ushort* WT; const float* bias; int wn0;
  if (QKV){
    int which = bn0 >> 8;
    WT = which == 0 ? W0 : (which == 1 ? W1p : W2p);
    bias = which == 0 ? B0 : (which == 1 ? B1p : B2p);
    wn0 = bn0 & 255;
  } else { WT = W0; bias = B0; wn0 = bn0; }

  int r4 = tid >> 2, c8 = (tid & 3) * 8;
  const ushort* ag = A + (long)(bm0 + r4) * K + c8;
  const ushort* bg = WT + (long)(wn0 + r4) * K + c8;

  f4v acc[2][2];
  #pragma unroll
  for (int i = 0; i < 2; ++i)
    #pragma unroll
    for (int j = 0; j < 2; ++j)
      acc[i][j] = (f4v){0.f, 0.f, 0.f, 0.f};

  int l16 = lane & 15, lg = lane >> 4;
  int arow0 = (wm * 32 + l16) * 48 + lg * 8;
  int brow0 = (wn * 32 + l16) * 48 + lg * 8;

  for (int k0 = 0; k0 < K; k0 += 32){
    b8v a8 = *(const b8v*)(ag + k0);
    b8v b8 = *(const b8v*)(bg + k0);
    __syncthreads();
    *(b8v*)&Al[r4 * 48 + c8] = a8;
    *(b8v*)&Bl[r4 * 48 + c8] = b8;
    __syncthreads();
    b8v a0 = *(const b8v*)&Al[arow0];
    b8v a1 = *(const b8v*)&Al[arow0 + 16 * 48];
    b8v b0 = *(const b8v*)&Bl[brow0];
    b8v b1 = *(const b8v*)&Bl[brow0 + 16 * 48];
    acc[0][0] = __builtin_amdgcn_mfma_f32_16x16x32_bf16(a0, b0, acc[0][0], 0, 0, 0);
    acc[0][1] = __builtin_amdgcn_mfma_f32_16x16x32_bf16(a0, b1, acc[0][1], 0, 0, 0);
    acc[1][0] = __builtin_amdgcn_mfma_f32_16x16x32_bf16(a1, b0, acc[1][0], 0, 0, 0);
    acc[1][1] = __builtin_amdgcn_mfma_f32_16x16x32_bf16(a1, b1, acc[1][1], 0, 0, 0);
  }
  #pragma unroll
  for (int fi = 0; fi < 2; ++fi)
    #pragma unroll
    for (int fj = 0; fj < 2; ++fj){
      int row0 = bm0 + wm * 32 + fi * 16 + lg * 4;
      int col = bn0 + wn * 32 + fj * 16 + l16;
      float vv[4];
      #pragma unroll
      for (int j = 0; j < 4; ++j) vv[j] = acc[fi][fj][j] + bias[QKV ? (col & 255) : col];
      if (QKV){
        int which = col >> 8, hh = (col >> 5) & 7, dk = col & 31;
        if (which == 2){
          ushort4 pk; pk.x = f2b(vv[0]); pk.y = f2b(vv[1]); pk.z = f2b(vv[2]); pk.w = f2b(vv[3]);
          *(ushort4*)(outB2 + (long)hh * 32768 + (long)dk * 1024 + row0) = pk;
        } else {
          #pragma unroll
          for (int j = 0; j < 4; ++j)
            outB[(long)which * 262144 + (long)hh * 32768 + (long)(row0 + j) * 32 + dk] = f2b(vv[j]);
        }
      } else {
        #pragma unroll
        for (int j = 0; j < 4; ++j){
          float v = vv[j];
          if (RELU) v = fmaxf(v, 0.f);
          long idx = (long)(row0 + j) * Nc + col;
          if (RESID) v += resid[idx];
          if (OUTF) outF[idx] = v;
          if (OUTB) outB[idx] = f2b(v);
        }
      }
    }
}

// ---------------- fully-fused MFMA flash attention (qr + flash + bins + combine)
// grid (N/32, H), 512 threads = 8 waves: 4-way j-split x 2-way i-split
__global__ __launch_bounds__(512)
void attn_kernel(const ushort* __restrict__ qb, const ushort* __restrict__ kb,
                 const ushort* __restrict__ vbt, const float* __restrict__ rke,
                 const float* __restrict__ rve,
                 const unsigned char* __restrict__ rel8, ushort* __restrict__ ob){
  __shared__ float q_l[AIB * 32];         // f32 q rows (for qr dots)
  __shared__ float qr_l[AIB * 40];        // qr bias per row
  __shared__ float prb[4 * AIB * 40];     // relation bins per (js,row)
  __shared__ uint  p_l[8 * 16 * 20];      // P^T repack, wave-private
  __shared__ float part_l[4 * AIB * 34];  // per (js,row): o[32], m, l
  __shared__ float wf_l[4 * AIB];
  __shared__ float lrow_l[AIB];

  int tid = threadIdx.x, lane = tid & 63, w = tid >> 6;
  int l16 = lane & 15, g = lane >> 4;
  int ib0 = blockIdx.x * AIB, h = blockIdx.y;
  int js = w >> 1, ig = w & 1;
  int ir = ig * 16 + l16;

  // stage q (f32) + zero bins
  if (tid < 256){
    int row = tid >> 3, d4 = (tid & 7) * 4;
    ushort4 u = *(const ushort4*)(qb + (long)((h << 10) + ib0 + row) * 32 + d4);
    q_l[row * 32 + d4 + 0] = b2f(u.x);
    q_l[row * 32 + d4 + 1] = b2f(u.y);
    q_l[row * 32 + d4 + 2] = b2f(u.z);
    q_l[row * 32 + d4 + 3] = b2f(u.w);
  }
  for (int idx = tid; idx < 4 * AIB * 40; idx += 512) prb[idx] = 0.f;
  __syncthreads();

  // qr[row][r] = SCL * q[row,:] . rke[r,:]
  for (int slot = tid; slot < AIB * 40; slot += 512){
    int row = slot / 40, r = slot - row * 40;
    if (r < R_){
      const float* qh = &q_l[row * 32];
      const float* e = rke + r * 32;
      float acc = 0.f;
      #pragma unroll
      for (int d = 0; d < 32; ++d) acc += qh[d] * e[d];
      qr_l[slot] = acc * SCL;
    }
  }
  __syncthreads();

  b8v qf = *(const b8v*)(qb + (long)((h << 10) + ib0 + ir) * 32 + g * 8);

  f4v oacc0 = (f4v){0.f,0.f,0.f,0.f}, oacc1 = (f4v){0.f,0.f,0.f,0.f};
  float m = -3.0e38f, lsum = 0.f;
  const float* qrr = &qr_l[ir * 40];
  float* prr = &prb[(js * AIB + ir) * 40];
  const unsigned char* relrow = rel8 + (long)(ib0 + ir) * N_ + js * 256;
  const ushort* kbh = kb + (long)(h << 10) * 32;
  const ushort* vth = vbt + (long)h * 32 * 1024;
  uint* pw = &p_l[w * 320 + l16 * 20];

  #pragma unroll
  for (int jt = 0; jt < 8; ++jt){
    int j0 = js * 256 + jt * 32;
    b8v kf0 = *(const b8v*)(kbh + (long)(j0 + l16) * 32 + g * 8);
    b8v kf1 = *(const b8v*)(kbh + (long)(j0 + 16 + l16) * 32 + g * 8);
    b8v vt0 = *(const b8v*)(vth + (long)l16 * 1024 + j0 + g * 8);
    b8v vt1 = *(const b8v*)(vth + (long)(16 + l16) * 1024 + j0 + g * 8);
    uint rr0 = *(const uint*)(relrow + jt * 32 + g * 4);
    uint rr1 = *(const uint*)(relrow + jt * 32 + 16 + g * 4);

    f4v z = (f4v){0.f,0.f,0.f,0.f};
    f4v s0 = __builtin_amdgcn_mfma_f32_16x16x32_bf16(kf0, qf, z, 0, 0, 0);
    f4v s1 = __builtin_amdgcn_mfma_f32_16x16x32_bf16(kf1, qf, z, 0, 0, 0);

    int rix[8];
    float sv[8];
    #pragma unroll
    for (int e = 0; e < 4; ++e){
      rix[e]     = (rr0 >> (8 * e)) & 255;
      rix[e + 4] = (rr1 >> (8 * e)) & 255;
      sv[e]     = s0[e] * SCL + qrr[rix[e]];
      sv[e + 4] = s1[e] * SCL + qrr[rix[e + 4]];
    }
    float tmax = sv[0];
    #pragma unroll
    for (int e = 1; e < 8; ++e) tmax = fmaxf(tmax, sv[e]);
    tmax = fmaxf(tmax, __shfl_xor(tmax, 16));
    tmax = fmaxf(tmax, __shfl_xor(tmax, 32));

    // defer-max: rescale only when max grows by > 12 (exp2 domain)
    if (tmax - m > 12.f){
      float f = ex2(m - tmax);
      oacc0 *= f; oacc1 *= f; lsum *= f;
      #pragma unroll
      for (int b2 = 0; b2 < 10; ++b2){
        int bi = g * 10 + b2;
        if (bi < R_) prr[bi] *= f;
      }
      m = tmax;
    }
    float p[8], ps = 0.f;
    #pragma unroll
    for (int e = 0; e < 8; ++e){ p[e] = ex2(sv[e] - m); ps += p[e]; }
    ps += __shfl_xor(ps, 16);
    ps += __shfl_xor(ps, 32);
    lsum += ps;
    #pragma unroll
    for (int e = 0; e < 8; ++e) lds_fadd(&prr[rix[e]], p[e]);

    // repack P^T to bf16 B-fragment via wave-private LDS (no barrier)
    uint pk0 = pk2b(p[0], p[1]), pk1 = pk2b(p[2], p[3]);
    uint pk2 = pk2b(p[4], p[5]), pk3 = pk2b(p[6], p[7]);
    *(u2v*)&pw[g * 2]     = (u2v){pk0, pk1};
    *(u2v*)&pw[8 + g * 2] = (u2v){pk2, pk3};
    b8v pf = *(const b8v*)&pw[g * 4];
    oacc0 = __builtin_amdgcn_mfma_f32_16x16x32_bf16(vt0, pf, oacc0, 0, 0, 0);
    oacc1 = __builtin_amdgcn_mfma_f32_16x16x32_bf16(vt1, pf, oacc1, 0, 0, 0);
  }

  // write per-wave partial into LDS
  {
    float* pp = &part_l[(js * AIB + ir) * 34];
    #pragma unroll
    for (int e = 0; e < 4; ++e){
      pp[g * 4 + e] = oacc0[e];
      pp[16 + g * 4 + e] = oacc1[e];
    }
    if (g == 0){ pp[32] = m; pp[33] = lsum; }
  }
  __syncthreads();

  // per-row combine weights
  if (tid < AIB){
    int row = tid;
    float ms[4], ls[4];
    float mstar = -3.0e38f;
    #pragma unroll
    for (int s = 0; s < 4; ++s){
      ms[s] = part_l[(s * AIB + row) * 34 + 32];
      ls[s] = part_l[(s * AIB + row) * 34 + 33];
      mstar = fmaxf(mstar, ms[s]);
    }
    float lstar = 0.f;
    #pragma unroll
    for (int s = 0; s < 4; ++s){
      float wfv = ex2(ms[s] - mstar);
      wf_l[s * AIB + row] = wfv;
      lstar += ls[s] * wfv;
    }
    lrow_l[row] = lstar;
  }
  __syncthreads();

  // merge bins across j-splits (into s=0 region)
  for (int slot = tid; slot < AIB * 40; slot += 512){
    int row = slot / 40;
    float acc = 0.f;
    #pragma unroll
    for (int s = 0; s < 4; ++s) acc += prb[(s * AIB) * 40 + slot] * wf_l[s * AIB + row];
    prb[slot] = acc;
  }
  __syncthreads();

  // final output: o = (sum_s wf*o_s + bins @ rve) / lstar
  for (int slot = tid; slot < AIB * 32; slot += 512){
    int row = slot >> 5, d = slot & 31;
    float o1 = 0.f;
    #pragma unroll
    for (int s = 0; s < 4; ++s) o1 += part_l[(s * AIB + row) * 34 + d] * wf_l[s * AIB + row];
    float o2 = 0.f;
    #pragma unroll
    for (int r = 0; r < R_; ++r) o2 += prb[row * 40 + r] * rve[r * 32 + d];
    float val = (o1 + o2) / lrow_l[row];
    ob[(long)(ib0 + row) * D_ + h * 32 + d] = f2b(val);
  }
}

extern "C" void kernel_launch(void* const* d_in, const int* in_sizes, int n_in,
                              void* d_out, int out_size, void* d_ws, size_t ws_size,
                              hipStream_t stream){
  const float* x    = (const float*)d_in[0];
  const int*   rel  = (const int*)d_in[1];
  const float* Wq   = (const float*)d_in[2];
  const float* bq   = (const float*)d_in[3];
  const float* Wk   = (const float*)d_in[4];
  const float* bk   = (const float*)d_in[5];
  const float* Wv   = (const float*)d_in[6];
  const float* bv   = (const float*)d_in[7];
  const float* Wo   = (const float*)d_in[8];
  const float* bo   = (const float*)d_in[9];
  const float* rke  = (const float*)d_in[10];
  const float* rve  = (const float*)d_in[11];
  const float* W1   = (const float*)d_in[12];
  const float* b1   = (const float*)d_in[13];
  const float* W2   = (const float*)d_in[14];
  const float* b2   = (const float*)d_in[15];
  const float* ln1g = (const float*)d_in[16];
  const float* ln1b = (const float*)d_in[17];
  const float* ln2g = (const float*)d_in[18];
  const float* ln2b = (const float*)d_in[19];
  const float* lnfg = (const float*)d_in[20];
  const float* lnfb = (const float*)d_in[21];

  char* wsb = (char*)d_ws;
  size_t off = 0;
  auto alloc = [&](size_t bytes){ void* p = wsb + off; off += (bytes + 255) & ~255ull; return p; };
  float*  xw   = (float*) alloc((size_t)N_ * D_ * 4);
  ushort* qkvb = (ushort*)alloc((size_t)3 * H_ * N_ * DK_ * 2);
  ushort* vbt  = (ushort*)alloc((size_t)H_ * DK_ * N_ * 2);
  ushort* xnb  = (ushort*)alloc((size_t)N_ * D_ * 2);
  ushort* obf  = (ushort*)alloc((size_t)N_ * D_ * 2);
  ushort* hidb = (ushort*)alloc((size_t)N_ * FF_ * 2);
  uint*   rel8 = (uint*)  alloc((size_t)N_ * N_);
  ushort* wqT  = (ushort*)alloc((size_t)L_ * D_ * D_ * 2);
  ushort* wkT  = (ushort*)alloc((size_t)L_ * D_ * D_ * 2);
  ushort* wvT  = (ushort*)alloc((size_t)L_ * D_ * D_ * 2);
  ushort* woT  = (ushort*)alloc((size_t)L_ * D_ * D_ * 2);
  ushort* w1T  = (ushort*)alloc((size_t)L_ * D_ * FF_ * 2);
  ushort* w2T  = (ushort*)alloc((size_t)L_ * D_ * FF_ * 2);
  (void)ws_size; (void)in_sizes; (void)n_in; (void)out_size;

  ushort* qb = qkvb;
  ushort* kb = qkvb + (size_t)H_ * N_ * DK_;

  dim3 tb(32, 8);
  wcast_kernel<<<dim3(D_/32,  D_/32,  L_), tb, 0, stream>>>(Wq, wqT, D_, D_);
  wcast_kernel<<<dim3(D_/32,  D_/32,  L_), tb, 0, stream>>>(Wk, wkT, D_, D_);
  wcast_kernel<<<dim3(D_/32,  D_/32,  L_), tb, 0, stream>>>(Wv, wvT, D_, D_);
  wcast_kernel<<<dim3(D_/32,  D_/32,  L_), tb, 0, stream>>>(Wo, woT, D_, D_);
  wcast_kernel<<<dim3(FF_/32, D_/32,  L_), tb, 0, stream>>>(W1, w1T, D_, FF_);
  wcast_kernel<<<dim3(D_/32,  FF_/32, L_), tb, 0, stream>>>(W2, w2T, FF_, D_);
  rel8_kernel<<<N_ * N_ / 1024, 256, 0, stream>>>(rel, rel8);

  hipMemcpyAsync(xw, x, (size_t)N_ * D_ * 4, hipMemcpyDeviceToDevice, stream);

  for (int l = 0; l < L_; ++l){
    ln_kernel<1><<<N_, 64, 0, stream>>>(xw, ln1g + l * D_, ln1b + l * D_, xnb, nullptr);
    gemm_kernel<1,0,0,0,1><<<dim3(768/64, N_/64), 256, 0, stream>>>(
        xnb, wqT + (size_t)l * D_ * D_, wkT + (size_t)l * D_ * D_, wvT + (size_t)l * D_ * D_,
        bq + l * D_, bk + l * D_, bv + l * D_,
        nullptr, nullptr, qkvb, vbt, N_, 768, D_);
    attn_kernel<<<dim3(N_/AIB, H_), 512, 0, stream>>>(
        qb, kb, vbt, rke + (size_t)l * R_ * DK_, rve + (size_t)l * R_ * DK_,
        (const unsigned char*)rel8, obf);
    gemm_kernel<0,0,1,1,0><<<dim3(D_/64, N_/64), 256, 0, stream>>>(
        obf, woT + (size_t)l * D_ * D_, nullptr, nullptr,
        bo + l * D_, nullptr, nullptr,
        xw, xw, nullptr, nullptr, N_, D_, D_);
    ln_kernel<1><<<N_, 64, 0, stream>>>(xw, ln2g + l * D_, ln2b + l * D_, xnb, nullptr);
    gemm_kernel<0,1,0,0,1><<<dim3(FF_/64, N_/64), 256, 0, stream>>>(
        xnb, w1T + (size_t)l * D_ * FF_, nullptr, nullptr,
        b1 + l * FF_, nullptr, nullptr,
        nullptr, nullptr, hidb, nullptr, N_, FF_, D_);
    gemm_kernel<0,0,1,1,0><<<dim3(D_/64, N_/64), 256, 0, stream>>>(
        hidb, w2T + (size_t)l * FF_ * D_, nullptr, nullptr,
        b2 + l * D_, nullptr, nullptr,
        xw, xw, nullptr, nullptr, N_, D_, FF_);
  }
  ln_kernel<0><<<N_, 64, 0, stream>>>(xw, lnfg, lnfb, nullptr, (float*)d_out);
}